// Round 3
// baseline (2311.603 us; speedup 1.0000x reference)
//
#include <hip/hip_runtime.h>
#include <float.h>

#define B8 8
#define NPTS 4096

// ---------------- split x[B,6,N] -> xyz[B,N,3], nrm[B,N,3] ----------------
__global__ void split_xyz_kernel(const float* __restrict__ x,
                                 float* __restrict__ xyz, float* __restrict__ nrm) {
  int g = blockIdx.x * 256 + threadIdx.x;
  if (g >= B8 * NPTS) return;
  int b = g / NPTS, n = g % NPTS;
  const float* xb = x + (size_t)b * 6 * NPTS;
  float* o1 = xyz + (size_t)g * 3;
  float* o2 = nrm + (size_t)g * 3;
  o1[0] = xb[0 * NPTS + n]; o1[1] = xb[1 * NPTS + n]; o1[2] = xb[2 * NPTS + n];
  o2[0] = xb[3 * NPTS + n]; o2[1] = xb[4 * NPTS + n]; o2[2] = xb[5 * NPTS + n];
}

// ---------------- DPP helpers (register-only cross-lane) ----------------
template <int CTRL, int RM>
__device__ __forceinline__ unsigned dppmov(unsigned v) {
  return (unsigned)__builtin_amdgcn_update_dpp((int)v, (int)v, CTRL, RM, 0xf, false);
}

// one reduction step: pull DPP-shifted (key,coords), keep max-key tuple
template <int CTRL, int RM>
__device__ __forceinline__ void red_step(unsigned& kh, unsigned& kl,
                                         float& x, float& y, float& z) {
  unsigned oh = dppmov<CTRL, RM>(kh);
  unsigned ol = dppmov<CTRL, RM>(kl);
  unsigned ox = dppmov<CTRL, RM>(__float_as_uint(x));
  unsigned oy = dppmov<CTRL, RM>(__float_as_uint(y));
  unsigned oz = dppmov<CTRL, RM>(__float_as_uint(z));
  unsigned long long ko = ((unsigned long long)oh << 32) | ol;
  unsigned long long k  = ((unsigned long long)kh << 32) | kl;
  bool c = ko > k;
  kh = c ? oh : kh; kl = c ? ol : kl;
  x = c ? __uint_as_float(ox) : x;
  y = c ? __uint_as_float(oy) : y;
  z = c ? __uint_as_float(oz) : z;
}

// ---------------- furthest point sampling v3 ----------------
// One block per batch, BLOCK*P == N. Key = (bits(dist)<<32)|~idx -> u64 max ==
// argmax with tie->lowest index. Candidate coords are carried through the
// reduction, so no LDS xyz table and no second LDS round-trip: per iteration
// it's dist-update -> DPP wave reduce -> lane63 LDS write -> barrier ->
// redundant NW-entry reduce (broadcast reads).
template <int BLOCK, int P>
__global__ __launch_bounds__(BLOCK) void fps3_kernel(const float* __restrict__ xyz,
                                                     int N, int S,
                                                     float* __restrict__ out_xyz) {
#pragma clang fp contract(off)
  constexpr int NW = BLOCK / 64;
  __shared__ unsigned wkh[2][NW], wkl[2][NW];
  __shared__ float wx[2][NW], wy[2][NW], wz[2][NW];
  int b = blockIdx.x, t = threadIdx.x;
  const float* p = xyz + (size_t)b * N * 3;
  float px[P], py[P], pz[P], dist[P];
#pragma unroll
  for (int j = 0; j < P; ++j) {
    int idx = t + j * BLOCK;
    px[j] = p[3 * idx]; py[j] = p[3 * idx + 1]; pz[j] = p[3 * idx + 2];
    dist[j] = 1e10f;
  }
  // first far point = index 0 (uniform broadcast load)
  float fx = p[0], fy = p[1], fz = p[2];
  for (int i = 0; i < S; ++i) {
    if (t == 0) {
      float* o = out_xyz + ((size_t)b * S + i) * 3;
      o[0] = fx; o[1] = fy; o[2] = fz;
    }
    unsigned long long best = 0ull;
    float bx = 0.f, by = 0.f, bz = 0.f;
#pragma unroll
    for (int j = 0; j < P; ++j) {
      int idx = t + j * BLOCK;
      float dx = px[j] - fx, dy = py[j] - fy, dz = pz[j] - fz;
      float d = dx * dx + dy * dy + dz * dz;
      float nd = fminf(dist[j], d);
      dist[j] = nd;
      unsigned long long key =
          ((unsigned long long)__float_as_uint(nd) << 32) | (unsigned)(~idx);
      bool c = key > best;
      best = c ? key : best;
      bx = c ? px[j] : bx; by = c ? py[j] : by; bz = c ? pz[j] : bz;
    }
    unsigned kh = (unsigned)(best >> 32), kl = (unsigned)best;
    // 64-lane max-reduce, result lands in lane 63 of each wave
    red_step<0x111, 0xf>(kh, kl, bx, by, bz);  // row_shr:1
    red_step<0x112, 0xf>(kh, kl, bx, by, bz);  // row_shr:2
    red_step<0x114, 0xf>(kh, kl, bx, by, bz);  // row_shr:4
    red_step<0x118, 0xf>(kh, kl, bx, by, bz);  // row_shr:8
    red_step<0x142, 0xa>(kh, kl, bx, by, bz);  // row_bcast:15 -> rows 1,3
    red_step<0x143, 0xc>(kh, kl, bx, by, bz);  // row_bcast:31 -> rows 2,3
    int buf = i & 1;
    if ((t & 63) == 63) {
      int w = t >> 6;
      wkh[buf][w] = kh; wkl[buf][w] = kl;
      wx[buf][w] = bx; wy[buf][w] = by; wz[buf][w] = bz;
    }
    __syncthreads();
    // all threads redundantly reduce the NW wave entries (broadcast LDS reads)
    unsigned gh = wkh[buf][0], gl = wkl[buf][0];
    float gx = wx[buf][0], gy = wy[buf][0], gz = wz[buf][0];
#pragma unroll
    for (int w = 1; w < NW; ++w) {
      unsigned oh = wkh[buf][w], ol = wkl[buf][w];
      unsigned long long ko = ((unsigned long long)oh << 32) | ol;
      unsigned long long k  = ((unsigned long long)gh << 32) | gl;
      bool c = ko > k;
      gh = c ? oh : gh; gl = c ? ol : gl;
      gx = c ? wx[buf][w] : gx; gy = c ? wy[buf][w] : gy; gz = c ? wz[buf][w] : gz;
    }
    fx = gx; fy = gy; fz = gz;
  }
}

// ---------------- kNN k=20: one wave per query, 20x argmin-with-exclusion ----------------
__global__ __launch_bounds__(64) void knn20_kernel(const float* __restrict__ q,
                                                   const float* __restrict__ ref,
                                                   int S, int M, int* __restrict__ nidx) {
#pragma clang fp contract(off)
  int bs = blockIdx.x;
  int b = bs / S;
  int t = threadIdx.x;
  __shared__ float sd[4096];
  const float* qp = q + (size_t)bs * 3;
  float qx = qp[0], qy = qp[1], qz = qp[2];
  float qq = qx * qx + qy * qy + qz * qz;
  const float* rp = ref + (size_t)b * M * 3;
  for (int i = t; i < M; i += 64) {
    float rx = rp[3 * i], ry = rp[3 * i + 1], rz = rp[3 * i + 2];
    float rr = rx * rx + ry * ry + rz * rz;
    float dot = qx * rx + qy * ry + qz * rz;
    sd[i] = qq - 2.0f * dot + rr;
  }
  __syncthreads();
  int* out = nidx + (size_t)bs * 20;
  for (int k = 0; k < 20; ++k) {
    float bv = FLT_MAX; int bi = 0x7fffffff;
    for (int i = t; i < M; i += 64) {
      float v = sd[i];
      if (v < bv || (v == bv && i < bi)) { bv = v; bi = i; }
    }
    for (int off = 32; off > 0; off >>= 1) {
      float ov = __shfl_down(bv, off);
      int oi = __shfl_down(bi, off);
      if (ov < bv || (ov == bv && oi < bi)) { bv = ov; bi = oi; }
    }
    bi = __shfl(bi, 0);
    if (t == 0) { out[k] = bi; sd[bi] = FLT_MAX; }
    __syncthreads();
  }
}

// ---------------- grouping: grp[b,s,k,:] = [xyz[nidx]-new_xyz (3), feats[nidx] (C)] ----------------
__global__ void group_kernel(const float* __restrict__ xyz, const float* __restrict__ feats,
                             const float* __restrict__ new_xyz, const int* __restrict__ nidx,
                             int M, int S, int C, float* __restrict__ grp, int total) {
  int g = blockIdx.x * 256 + threadIdx.x;
  if (g >= total) return;
  int Cin = 3 + C;
  int c = g % Cin;
  int bsk = g / Cin;
  int bs = bsk / 20;
  int b = bs / S;
  int id = nidx[bsk];
  float v;
  if (c < 3)
    v = xyz[((size_t)b * M + id) * 3 + c] - new_xyz[(size_t)bs * 3 + c];
  else
    v = feats[((size_t)b * M + id) * C + (c - 3)];
  grp[g] = v;
}

// ---------------- GEMM: C[M,N] = act(A[M,K] @ W[K,N] + bias) ----------------
__global__ __launch_bounds__(256) void gemm_kernel(const float* __restrict__ A,
                                                   const float* __restrict__ Wm,
                                                   const float* __restrict__ bias,
                                                   float* __restrict__ C,
                                                   int M, int N, int K, int relu) {
  __shared__ float As[16][64];
  __shared__ float Bs[16][64];
  int tx = threadIdx.x & 15, ty = threadIdx.x >> 4;
  int rowBase = blockIdx.y * 64;
  int colBase = blockIdx.x * 64;
  float acc[4][4] = {};
  for (int k0 = 0; k0 < K; k0 += 16) {
    for (int l = threadIdx.x; l < 1024; l += 256) {
      int m = l >> 4, kk = l & 15;
      int rr = rowBase + m, kq = k0 + kk;
      As[kk][m] = (rr < M && kq < K) ? A[(size_t)rr * K + kq] : 0.0f;
    }
    for (int l = threadIdx.x; l < 1024; l += 256) {
      int kk = l >> 6, n = l & 63;
      int kq = k0 + kk, cc = colBase + n;
      Bs[kk][n] = (kq < K && cc < N) ? Wm[(size_t)kq * N + cc] : 0.0f;
    }
    __syncthreads();
#pragma unroll
    for (int kk = 0; kk < 16; ++kk) {
      const float4 av = *reinterpret_cast<const float4*>(&As[kk][ty * 4]);
      const float4 bv = *reinterpret_cast<const float4*>(&Bs[kk][tx * 4]);
      acc[0][0] += av.x * bv.x; acc[0][1] += av.x * bv.y; acc[0][2] += av.x * bv.z; acc[0][3] += av.x * bv.w;
      acc[1][0] += av.y * bv.x; acc[1][1] += av.y * bv.y; acc[1][2] += av.y * bv.z; acc[1][3] += av.y * bv.w;
      acc[2][0] += av.z * bv.x; acc[2][1] += av.z * bv.y; acc[2][2] += av.z * bv.z; acc[2][3] += av.z * bv.w;
      acc[3][0] += av.w * bv.x; acc[3][1] += av.w * bv.y; acc[3][2] += av.w * bv.z; acc[3][3] += av.w * bv.w;
    }
    __syncthreads();
  }
#pragma unroll
  for (int i = 0; i < 4; ++i) {
    int row = rowBase + ty * 4 + i;
    if (row >= M) continue;
#pragma unroll
    for (int j = 0; j < 4; ++j) {
      int col = colBase + tx * 4 + j;
      if (col >= N) continue;
      float v = acc[i][j] + bias[col];
      if (relu) v = fmaxf(v, 0.0f);
      C[(size_t)row * N + col] = v;
    }
  }
}

// ---------------- maxpool over K=20 neighbors ----------------
__global__ void maxpool_kernel(const float* __restrict__ H, int SB, int C,
                               float* __restrict__ f) {
  int g = blockIdx.x * 256 + threadIdx.x;
  if (g >= SB * C) return;
  int d = g % C;
  int bs = g / C;
  const float* h = H + (size_t)bs * 20 * C + d;
  float m = h[0];
#pragma unroll
  for (int k = 1; k < 20; ++k) m = fmaxf(m, h[(size_t)k * C]);
  f[g] = m;
}

// ---------------- kNN k=3 + inverse-distance weights (one thread per query) ----------------
__global__ void knn3_kernel(const float* __restrict__ q, const float* __restrict__ ref,
                            int Sq, int M, int* __restrict__ idx3, float* __restrict__ w3,
                            int total) {
#pragma clang fp contract(off)
  int g = blockIdx.x * 256 + threadIdx.x;
  if (g >= total) return;
  int b = g / Sq;
  const float* qp = q + (size_t)g * 3;
  float qx = qp[0], qy = qp[1], qz = qp[2];
  float qq = qx * qx + qy * qy + qz * qz;
  const float* rp = ref + (size_t)b * M * 3;
  float v0 = FLT_MAX, v1 = FLT_MAX, v2 = FLT_MAX;
  int i0 = 0, i1 = 0, i2 = 0;
  for (int i = 0; i < M; ++i) {
    float rx = rp[3 * i], ry = rp[3 * i + 1], rz = rp[3 * i + 2];
    float d = qq - 2.0f * (qx * rx + qy * ry + qz * rz) + (rx * rx + ry * ry + rz * rz);
    if (d < v2) {
      if (d < v1) {
        if (d < v0) { v2 = v1; i2 = i1; v1 = v0; i1 = i0; v0 = d; i0 = i; }
        else { v2 = v1; i2 = i1; v1 = d; i1 = i; }
      } else { v2 = d; i2 = i; }
    }
  }
  int ii[3] = {i0, i1, i2};
  float w[3];
  float wsum = 0.0f;
#pragma unroll
  for (int k = 0; k < 3; ++k) {
    const float* r = rp + (size_t)ii[k] * 3;
    float dx = r[0] - qx, dy = r[1] - qy, dz = r[2] - qz;
    float d = dx * dx + dy * dy + dz * dz;
    w[k] = 1.0f / (d + 1e-8f);
    wsum += w[k];
  }
#pragma unroll
  for (int k = 0; k < 3; ++k) {
    idx3[(size_t)g * 3 + k] = ii[k];
    w3[(size_t)g * 3 + k] = w[k] / wsum;
  }
}

// ---------------- FP: interp + concat skip -> cat[B,S,Cr+Cs] ----------------
__global__ void fp_cat_kernel(const float* __restrict__ fr, const int* __restrict__ idx3,
                              const float* __restrict__ w3, const float* __restrict__ skip,
                              const float* __restrict__ cls, const float* __restrict__ xyz,
                              const float* __restrict__ nrm,
                              int Sq, int Mr, int Cr, int Cs, int mode,
                              float* __restrict__ cat, int total) {
  int g = blockIdx.x * 256 + threadIdx.x;
  if (g >= total) return;
  int Cin = Cr + Cs;
  int c = g % Cin;
  int bs = g / Cin;
  int b = bs / Sq;
  float v;
  if (c < Cr) {
    const int* ii = idx3 + (size_t)bs * 3;
    const float* ww = w3 + (size_t)bs * 3;
    const float* fb = fr + (size_t)b * Mr * Cr;
    v = ww[0] * fb[(size_t)ii[0] * Cr + c];
    v += ww[1] * fb[(size_t)ii[1] * Cr + c];
    v += ww[2] * fb[(size_t)ii[2] * Cr + c];
  } else {
    int cc = c - Cr;
    if (mode == 0) {
      v = skip[(size_t)bs * Cs + cc];
    } else {
      if (cc < 16) v = cls[(size_t)b * 16 + cc];
      else if (cc < 19) v = xyz[(size_t)bs * 3 + (cc - 16)];
      else v = nrm[(size_t)bs * 3 + (cc - 19)];
    }
  }
  cat[g] = v;
}

// ---------------- transpose g0 [B,N,128] -> out2 [B,128,N] ----------------
__global__ __launch_bounds__(256) void transpose_g0_kernel(const float* __restrict__ g0,
                                                           float* __restrict__ out2) {
  __shared__ float tile[32][33];
  int n0 = blockIdx.x * 32, c0 = blockIdx.y * 32, b = blockIdx.z;
  int tx = threadIdx.x & 31, ty = threadIdx.x >> 5;  // ty 0..7
#pragma unroll
  for (int j = 0; j < 32; j += 8)
    tile[ty + j][tx] = g0[((size_t)b * NPTS + n0 + ty + j) * 128 + c0 + tx];
  __syncthreads();
#pragma unroll
  for (int j = 0; j < 32; j += 8)
    out2[((size_t)b * 128 + c0 + ty + j) * NPTS + n0 + tx] = tile[tx][ty + j];
}

// ---------------- host-side orchestration ----------------
static inline int cdiv(int a, int b) { return (a + b - 1) / b; }

extern "C" void kernel_launch(void* const* d_in, const int* in_sizes, int n_in,
                              void* d_out, int out_size, void* d_ws, size_t ws_size,
                              hipStream_t stream) {
  const float* x    = (const float*)d_in[0];
  const float* cls  = (const float*)d_in[1];
  const float* W0 = (const float*)d_in[2];  const float* b0 = (const float*)d_in[3];
  const float* W1 = (const float*)d_in[4];  const float* b1 = (const float*)d_in[5];
  const float* W2 = (const float*)d_in[6];  const float* b2 = (const float*)d_in[7];
  const float* W3 = (const float*)d_in[8];  const float* b3 = (const float*)d_in[9];
  const float* F3 = (const float*)d_in[10]; const float* fb3 = (const float*)d_in[11];
  const float* F2 = (const float*)d_in[12]; const float* fb2 = (const float*)d_in[13];
  const float* F1 = (const float*)d_in[14]; const float* fb1 = (const float*)d_in[15];
  const float* F0 = (const float*)d_in[16]; const float* fb0 = (const float*)d_in[17];
  const float* Wseg = (const float*)d_in[18]; const float* bseg = (const float*)d_in[19];
  float* out = (float*)d_out;

  float* ws = (float*)d_ws;
  size_t off = 0;
  auto alloc = [&](size_t n) { float* p = ws + off; off += (n + 3) & ~(size_t)3; return p; };
  float* xyz = alloc(8 * 4096 * 3);
  float* nrm = alloc(8 * 4096 * 3);
  float* x1 = alloc(8 * 512 * 3);  float* f1 = alloc(8 * 512 * 64);
  float* x2 = alloc(8 * 256 * 3);  float* f2 = alloc(8 * 256 * 128);
  float* x3 = alloc(8 * 128 * 3);  float* f3 = alloc(8 * 128 * 256);
  float* x4 = alloc(8 * 64 * 3);   float* f4 = alloc(8 * 64 * 512);
  float* g3 = alloc(8 * 128 * 512);
  float* g2 = alloc(8 * 256 * 256);
  float* g1 = alloc(8 * 512 * 128);
  float* g0 = alloc(8 * 4096 * 128);
  float* w3buf = alloc(8 * 4096 * 3);
  float* grpbuf = alloc(8 * 4096 * 150);       // grp / cat scratch
  float* Hbuf = alloc(8 * 512 * 20 * 64);      // H scratch
  int* nidx = (int*)alloc(8 * 512 * 20);
  int* idx3 = (int*)alloc(8 * 4096 * 3);

  // 0. split/transpose input
  split_xyz_kernel<<<cdiv(8 * 4096, 256), 256, 0, stream>>>(x, xyz, nrm);

  // ---- SA1: 4096 -> 512, C 3 -> 64 (Cin 6) ----
  fps3_kernel<512, 8><<<8, 512, 0, stream>>>(xyz, 4096, 512, x1);
  knn20_kernel<<<8 * 512, 64, 0, stream>>>(x1, xyz, 512, 4096, nidx);
  {
    int total = 8 * 512 * 20 * 6;
    group_kernel<<<cdiv(total, 256), 256, 0, stream>>>(xyz, nrm, x1, nidx, 4096, 512, 3, grpbuf, total);
    dim3 grid(cdiv(64, 64), cdiv(8 * 512 * 20, 64));
    gemm_kernel<<<grid, 256, 0, stream>>>(grpbuf, W0, b0, Hbuf, 8 * 512 * 20, 64, 6, 1);
    int tp = 8 * 512 * 64;
    maxpool_kernel<<<cdiv(tp, 256), 256, 0, stream>>>(Hbuf, 8 * 512, 64, f1);
  }

  // ---- SA2: 512 -> 256, C 64 -> 128 (Cin 67) ----
  fps3_kernel<512, 1><<<8, 512, 0, stream>>>(x1, 512, 256, x2);
  knn20_kernel<<<8 * 256, 64, 0, stream>>>(x2, x1, 256, 512, nidx);
  {
    int total = 8 * 256 * 20 * 67;
    group_kernel<<<cdiv(total, 256), 256, 0, stream>>>(x1, f1, x2, nidx, 512, 256, 64, grpbuf, total);
    dim3 grid(cdiv(128, 64), cdiv(8 * 256 * 20, 64));
    gemm_kernel<<<grid, 256, 0, stream>>>(grpbuf, W1, b1, Hbuf, 8 * 256 * 20, 128, 67, 1);
    int tp = 8 * 256 * 128;
    maxpool_kernel<<<cdiv(tp, 256), 256, 0, stream>>>(Hbuf, 8 * 256, 128, f2);
  }

  // ---- SA3: 256 -> 128, C 128 -> 256 (Cin 131) ----
  fps3_kernel<256, 1><<<8, 256, 0, stream>>>(x2, 256, 128, x3);
  knn20_kernel<<<8 * 128, 64, 0, stream>>>(x3, x2, 128, 256, nidx);
  {
    int total = 8 * 128 * 20 * 131;
    group_kernel<<<cdiv(total, 256), 256, 0, stream>>>(x2, f2, x3, nidx, 256, 128, 128, grpbuf, total);
    dim3 grid(cdiv(256, 64), cdiv(8 * 128 * 20, 64));
    gemm_kernel<<<grid, 256, 0, stream>>>(grpbuf, W2, b2, Hbuf, 8 * 128 * 20, 256, 131, 1);
    int tp = 8 * 128 * 256;
    maxpool_kernel<<<cdiv(tp, 256), 256, 0, stream>>>(Hbuf, 8 * 128, 256, f3);
  }

  // ---- SA4: 128 -> 64, C 256 -> 512 (Cin 259) ----
  fps3_kernel<128, 1><<<8, 128, 0, stream>>>(x3, 128, 64, x4);
  knn20_kernel<<<8 * 64, 64, 0, stream>>>(x4, x3, 64, 128, nidx);
  {
    int total = 8 * 64 * 20 * 259;
    group_kernel<<<cdiv(total, 256), 256, 0, stream>>>(x3, f3, x4, nidx, 128, 64, 256, grpbuf, total);
    dim3 grid(cdiv(512, 64), cdiv(8 * 64 * 20, 64));
    gemm_kernel<<<grid, 256, 0, stream>>>(grpbuf, W3, b3, Hbuf, 8 * 64 * 20, 512, 259, 1);
    int tp = 8 * 64 * 512;
    maxpool_kernel<<<cdiv(tp, 256), 256, 0, stream>>>(Hbuf, 8 * 64, 512, f4);
  }

  // ---- FP3: interp f4 (x4->x3) + skip f3 -> g3 [B,128,512] ----
  knn3_kernel<<<cdiv(8 * 128, 256), 256, 0, stream>>>(x3, x4, 128, 64, idx3, w3buf, 8 * 128);
  {
    int total = 8 * 128 * 768;
    fp_cat_kernel<<<cdiv(total, 256), 256, 0, stream>>>(f4, idx3, w3buf, f3, nullptr, nullptr, nullptr,
                                                        128, 64, 512, 256, 0, grpbuf, total);
    dim3 grid(cdiv(512, 64), cdiv(8 * 128, 64));
    gemm_kernel<<<grid, 256, 0, stream>>>(grpbuf, F3, fb3, g3, 8 * 128, 512, 768, 1);
  }

  // ---- FP2: interp g3 (x3->x2) + skip f2 -> g2 [B,256,256] ----
  knn3_kernel<<<cdiv(8 * 256, 256), 256, 0, stream>>>(x2, x3, 256, 128, idx3, w3buf, 8 * 256);
  {
    int total = 8 * 256 * 640;
    fp_cat_kernel<<<cdiv(total, 256), 256, 0, stream>>>(g3, idx3, w3buf, f2, nullptr, nullptr, nullptr,
                                                        256, 128, 512, 128, 0, grpbuf, total);
    dim3 grid(cdiv(256, 64), cdiv(8 * 256, 64));
    gemm_kernel<<<grid, 256, 0, stream>>>(grpbuf, F2, fb2, g2, 8 * 256, 256, 640, 1);
  }

  // ---- FP1: interp g2 (x2->x1) + skip f1 -> g1 [B,512,128] ----
  knn3_kernel<<<cdiv(8 * 512, 256), 256, 0, stream>>>(x1, x2, 512, 256, idx3, w3buf, 8 * 512);
  {
    int total = 8 * 512 * 320;
    fp_cat_kernel<<<cdiv(total, 256), 256, 0, stream>>>(g2, idx3, w3buf, f1, nullptr, nullptr, nullptr,
                                                        512, 256, 256, 64, 0, grpbuf, total);
    dim3 grid(cdiv(128, 64), cdiv(8 * 512, 64));
    gemm_kernel<<<grid, 256, 0, stream>>>(grpbuf, F1, fb1, g1, 8 * 512, 128, 320, 1);
  }

  // ---- FP0: interp g1 (x1->xyz) + skip [cls,xyz,nrm] -> g0 [B,4096,128] ----
  knn3_kernel<<<cdiv(8 * 4096, 256), 256, 0, stream>>>(xyz, x1, 4096, 512, idx3, w3buf, 8 * 4096);
  {
    int total = 8 * 4096 * 150;
    fp_cat_kernel<<<cdiv(total, 256), 256, 0, stream>>>(g1, idx3, w3buf, nullptr, cls, xyz, nrm,
                                                        4096, 512, 128, 22, 1, grpbuf, total);
    dim3 grid(cdiv(128, 64), cdiv(8 * 4096, 64));
    gemm_kernel<<<grid, 256, 0, stream>>>(grpbuf, F0, fb0, g0, 8 * 4096, 128, 150, 1);
  }

  // ---- seg head: out1 = g0 @ Wseg + bseg (no relu) ----
  {
    dim3 grid(cdiv(50, 64), cdiv(8 * 4096, 64));
    gemm_kernel<<<grid, 256, 0, stream>>>(g0, Wseg, bseg, out, 8 * 4096, 50, 128, 0);
  }
  // ---- out2 = transpose(g0) ----
  transpose_g0_kernel<<<dim3(128, 4, 8), 256, 0, stream>>>(g0, out + (size_t)8 * 4096 * 50);
}

// Round 4
// 1726.932 us; speedup vs baseline: 1.3386x; 1.3386x over previous
//
#include <hip/hip_runtime.h>
#include <float.h>

#define B8 8
#define NPTS 4096

// ---------------- split x[B,6,N] -> xyz[B,N,3], nrm[B,N,3] ----------------
__global__ void split_xyz_kernel(const float* __restrict__ x,
                                 float* __restrict__ xyz, float* __restrict__ nrm) {
  int g = blockIdx.x * 256 + threadIdx.x;
  if (g >= B8 * NPTS) return;
  int b = g / NPTS, n = g % NPTS;
  const float* xb = x + (size_t)b * 6 * NPTS;
  float* o1 = xyz + (size_t)g * 3;
  float* o2 = nrm + (size_t)g * 3;
  o1[0] = xb[0 * NPTS + n]; o1[1] = xb[1 * NPTS + n]; o1[2] = xb[2 * NPTS + n];
  o2[0] = xb[3 * NPTS + n]; o2[1] = xb[4 * NPTS + n]; o2[2] = xb[5 * NPTS + n];
}

// ---------------- DPP helpers (register-only cross-lane) ----------------
template <int CTRL, int RM>
__device__ __forceinline__ unsigned dppmov(unsigned v) {
  return (unsigned)__builtin_amdgcn_update_dpp((int)v, (int)v, CTRL, RM, 0xf, false);
}

// key-only reduction step: pull DPP-shifted u64 key, keep max
template <int CTRL, int RM>
__device__ __forceinline__ void red_key(unsigned& kh, unsigned& kl) {
  unsigned oh = dppmov<CTRL, RM>(kh);
  unsigned ol = dppmov<CTRL, RM>(kl);
  unsigned long long ko = ((unsigned long long)oh << 32) | ol;
  unsigned long long k  = ((unsigned long long)kh << 32) | kl;
  bool c = ko > k;
  kh = c ? oh : kh;
  kl = c ? ol : kl;
}

// ---------------- furthest point sampling v4 ----------------
// One block per batch, BLOCK*P == N. Key = (bits(dist)<<32)|~idx -> u64 max ==
// argmax with tie->lowest index. Keys-only through both reduction stages
// (DPP wave reduce, then NW u64s via b128 LDS reads, reduced redundantly by
// all threads); winner coords via ONE ds_read_b128 from a float4 LDS table.
template <int BLOCK, int P>
__global__ __launch_bounds__(BLOCK) void fps4_kernel(const float* __restrict__ xyz,
                                                     int N, int S,
                                                     float* __restrict__ out_xyz) {
#pragma clang fp contract(off)
  constexpr int NW = BLOCK / 64;
  __shared__ float4 pts[BLOCK * P];
  __shared__ alignas(16) unsigned long long wkey[2][NW];
  int b = blockIdx.x, t = threadIdx.x;
  const float* p = xyz + (size_t)b * N * 3;
  float px[P], py[P], pz[P], dist[P];
#pragma unroll
  for (int j = 0; j < P; ++j) {
    int idx = t + j * BLOCK;
    float a = p[3 * idx], bb = p[3 * idx + 1], c = p[3 * idx + 2];
    px[j] = a; py[j] = bb; pz[j] = c;
    pts[idx] = make_float4(a, bb, c, 0.f);
    dist[j] = 1e10f;
  }
  __syncthreads();
  // first far point = index 0 (uniform broadcast load)
  float fx = p[0], fy = p[1], fz = p[2];
  for (int i = 0; i < S; ++i) {
    if (t == 0) {
      float* o = out_xyz + ((size_t)b * S + i) * 3;
      o[0] = fx; o[1] = fy; o[2] = fz;
    }
    unsigned long long best = 0ull;
#pragma unroll
    for (int j = 0; j < P; ++j) {
      int idx = t + j * BLOCK;
      float dx = px[j] - fx, dy = py[j] - fy, dz = pz[j] - fz;
      float d = dx * dx + dy * dy + dz * dz;
      float nd = fminf(dist[j], d);
      dist[j] = nd;
      unsigned long long key =
          ((unsigned long long)__float_as_uint(nd) << 32) | (unsigned)(~idx);
      best = (key > best) ? key : best;
    }
    unsigned kh = (unsigned)(best >> 32), kl = (unsigned)best;
    // 64-lane max-reduce, result lands in lane 63 of each wave
    red_key<0x111, 0xf>(kh, kl);  // row_shr:1
    red_key<0x112, 0xf>(kh, kl);  // row_shr:2
    red_key<0x114, 0xf>(kh, kl);  // row_shr:4
    red_key<0x118, 0xf>(kh, kl);  // row_shr:8
    red_key<0x142, 0xa>(kh, kl);  // row_bcast:15 -> rows 1,3
    red_key<0x143, 0xc>(kh, kl);  // row_bcast:31 -> rows 2,3
    int buf = i & 1;
    if ((t & 63) == 63)
      wkey[buf][t >> 6] = ((unsigned long long)kh << 32) | kl;
    __syncthreads();
    // all threads redundantly reduce the NW wave keys (vectorized broadcast)
    unsigned long long g = 0ull;
    const ulonglong2* wk2 = (const ulonglong2*)&wkey[buf][0];
#pragma unroll
    for (int w = 0; w < NW / 2; ++w) {
      ulonglong2 e = wk2[w];
      unsigned long long m = (e.x > e.y) ? e.x : e.y;
      g = (m > g) ? m : g;
    }
    int far = (int)~(unsigned)g;
    float4 f = pts[far];
    fx = f.x; fy = f.y; fz = f.z;
  }
}

// ---------------- kNN k=20: one wave per query, 20x argmin-with-exclusion ----------------
__global__ __launch_bounds__(64) void knn20_kernel(const float* __restrict__ q,
                                                   const float* __restrict__ ref,
                                                   int S, int M, int* __restrict__ nidx) {
#pragma clang fp contract(off)
  int bs = blockIdx.x;
  int b = bs / S;
  int t = threadIdx.x;
  __shared__ float sd[4096];
  const float* qp = q + (size_t)bs * 3;
  float qx = qp[0], qy = qp[1], qz = qp[2];
  float qq = qx * qx + qy * qy + qz * qz;
  const float* rp = ref + (size_t)b * M * 3;
  for (int i = t; i < M; i += 64) {
    float rx = rp[3 * i], ry = rp[3 * i + 1], rz = rp[3 * i + 2];
    float rr = rx * rx + ry * ry + rz * rz;
    float dot = qx * rx + qy * ry + qz * rz;
    sd[i] = qq - 2.0f * dot + rr;
  }
  __syncthreads();
  int* out = nidx + (size_t)bs * 20;
  for (int k = 0; k < 20; ++k) {
    float bv = FLT_MAX; int bi = 0x7fffffff;
    for (int i = t; i < M; i += 64) {
      float v = sd[i];
      if (v < bv || (v == bv && i < bi)) { bv = v; bi = i; }
    }
    for (int off = 32; off > 0; off >>= 1) {
      float ov = __shfl_down(bv, off);
      int oi = __shfl_down(bi, off);
      if (ov < bv || (ov == bv && oi < bi)) { bv = ov; bi = oi; }
    }
    bi = __shfl(bi, 0);
    if (t == 0) { out[k] = bi; sd[bi] = FLT_MAX; }
    __syncthreads();
  }
}

// ---------------- grouping: grp[b,s,k,:] = [xyz[nidx]-new_xyz (3), feats[nidx] (C)] ----------------
__global__ void group_kernel(const float* __restrict__ xyz, const float* __restrict__ feats,
                             const float* __restrict__ new_xyz, const int* __restrict__ nidx,
                             int M, int S, int C, float* __restrict__ grp, int total) {
  int g = blockIdx.x * 256 + threadIdx.x;
  if (g >= total) return;
  int Cin = 3 + C;
  int c = g % Cin;
  int bsk = g / Cin;
  int bs = bsk / 20;
  int b = bs / S;
  int id = nidx[bsk];
  float v;
  if (c < 3)
    v = xyz[((size_t)b * M + id) * 3 + c] - new_xyz[(size_t)bs * 3 + c];
  else
    v = feats[((size_t)b * M + id) * C + (c - 3)];
  grp[g] = v;
}

// ---------------- GEMM: C[M,N] = act(A[M,K] @ W[K,N] + bias) ----------------
// As padded to [16][68]: write bank (4*kk+m)%32 -> 2-way max (free);
// rows are 272 B so float4 reads stay 16B-aligned.
__global__ __launch_bounds__(256) void gemm_kernel(const float* __restrict__ A,
                                                   const float* __restrict__ Wm,
                                                   const float* __restrict__ bias,
                                                   float* __restrict__ C,
                                                   int M, int N, int K, int relu) {
  __shared__ alignas(16) float As[16][68];
  __shared__ float Bs[16][64];
  int tx = threadIdx.x & 15, ty = threadIdx.x >> 4;
  int rowBase = blockIdx.y * 64;
  int colBase = blockIdx.x * 64;
  float acc[4][4] = {};
  for (int k0 = 0; k0 < K; k0 += 16) {
    for (int l = threadIdx.x; l < 1024; l += 256) {
      int m = l >> 4, kk = l & 15;
      int rr = rowBase + m, kq = k0 + kk;
      As[kk][m] = (rr < M && kq < K) ? A[(size_t)rr * K + kq] : 0.0f;
    }
    for (int l = threadIdx.x; l < 1024; l += 256) {
      int kk = l >> 6, n = l & 63;
      int kq = k0 + kk, cc = colBase + n;
      Bs[kk][n] = (kq < K && cc < N) ? Wm[(size_t)kq * N + cc] : 0.0f;
    }
    __syncthreads();
#pragma unroll
    for (int kk = 0; kk < 16; ++kk) {
      const float4 av = *reinterpret_cast<const float4*>(&As[kk][ty * 4]);
      const float4 bv = *reinterpret_cast<const float4*>(&Bs[kk][tx * 4]);
      acc[0][0] += av.x * bv.x; acc[0][1] += av.x * bv.y; acc[0][2] += av.x * bv.z; acc[0][3] += av.x * bv.w;
      acc[1][0] += av.y * bv.x; acc[1][1] += av.y * bv.y; acc[1][2] += av.y * bv.z; acc[1][3] += av.y * bv.w;
      acc[2][0] += av.z * bv.x; acc[2][1] += av.z * bv.y; acc[2][2] += av.z * bv.z; acc[2][3] += av.z * bv.w;
      acc[3][0] += av.w * bv.x; acc[3][1] += av.w * bv.y; acc[3][2] += av.w * bv.z; acc[3][3] += av.w * bv.w;
    }
    __syncthreads();
  }
#pragma unroll
  for (int i = 0; i < 4; ++i) {
    int row = rowBase + ty * 4 + i;
    if (row >= M) continue;
#pragma unroll
    for (int j = 0; j < 4; ++j) {
      int col = colBase + tx * 4 + j;
      if (col >= N) continue;
      float v = acc[i][j] + bias[col];
      if (relu) v = fmaxf(v, 0.0f);
      C[(size_t)row * N + col] = v;
    }
  }
}

// ---------------- maxpool over K=20 neighbors ----------------
__global__ void maxpool_kernel(const float* __restrict__ H, int SB, int C,
                               float* __restrict__ f) {
  int g = blockIdx.x * 256 + threadIdx.x;
  if (g >= SB * C) return;
  int d = g % C;
  int bs = g / C;
  const float* h = H + (size_t)bs * 20 * C + d;
  float m = h[0];
#pragma unroll
  for (int k = 1; k < 20; ++k) m = fmaxf(m, h[(size_t)k * C]);
  f[g] = m;
}

// ---------------- kNN k=3 + inverse-distance weights (one thread per query) ----------------
__global__ void knn3_kernel(const float* __restrict__ q, const float* __restrict__ ref,
                            int Sq, int M, int* __restrict__ idx3, float* __restrict__ w3,
                            int total) {
#pragma clang fp contract(off)
  int g = blockIdx.x * 256 + threadIdx.x;
  if (g >= total) return;
  int b = g / Sq;
  const float* qp = q + (size_t)g * 3;
  float qx = qp[0], qy = qp[1], qz = qp[2];
  float qq = qx * qx + qy * qy + qz * qz;
  const float* rp = ref + (size_t)b * M * 3;
  float v0 = FLT_MAX, v1 = FLT_MAX, v2 = FLT_MAX;
  int i0 = 0, i1 = 0, i2 = 0;
  for (int i = 0; i < M; ++i) {
    float rx = rp[3 * i], ry = rp[3 * i + 1], rz = rp[3 * i + 2];
    float d = qq - 2.0f * (qx * rx + qy * ry + qz * rz) + (rx * rx + ry * ry + rz * rz);
    if (d < v2) {
      if (d < v1) {
        if (d < v0) { v2 = v1; i2 = i1; v1 = v0; i1 = i0; v0 = d; i0 = i; }
        else { v2 = v1; i2 = i1; v1 = d; i1 = i; }
      } else { v2 = d; i2 = i; }
    }
  }
  int ii[3] = {i0, i1, i2};
  float w[3];
  float wsum = 0.0f;
#pragma unroll
  for (int k = 0; k < 3; ++k) {
    const float* r = rp + (size_t)ii[k] * 3;
    float dx = r[0] - qx, dy = r[1] - qy, dz = r[2] - qz;
    float d = dx * dx + dy * dy + dz * dz;
    w[k] = 1.0f / (d + 1e-8f);
    wsum += w[k];
  }
#pragma unroll
  for (int k = 0; k < 3; ++k) {
    idx3[(size_t)g * 3 + k] = ii[k];
    w3[(size_t)g * 3 + k] = w[k] / wsum;
  }
}

// ---------------- FP: interp + concat skip -> cat[B,S,Cr+Cs] ----------------
__global__ void fp_cat_kernel(const float* __restrict__ fr, const int* __restrict__ idx3,
                              const float* __restrict__ w3, const float* __restrict__ skip,
                              const float* __restrict__ cls, const float* __restrict__ xyz,
                              const float* __restrict__ nrm,
                              int Sq, int Mr, int Cr, int Cs, int mode,
                              float* __restrict__ cat, int total) {
  int g = blockIdx.x * 256 + threadIdx.x;
  if (g >= total) return;
  int Cin = Cr + Cs;
  int c = g % Cin;
  int bs = g / Cin;
  int b = bs / Sq;
  float v;
  if (c < Cr) {
    const int* ii = idx3 + (size_t)bs * 3;
    const float* ww = w3 + (size_t)bs * 3;
    const float* fb = fr + (size_t)b * Mr * Cr;
    v = ww[0] * fb[(size_t)ii[0] * Cr + c];
    v += ww[1] * fb[(size_t)ii[1] * Cr + c];
    v += ww[2] * fb[(size_t)ii[2] * Cr + c];
  } else {
    int cc = c - Cr;
    if (mode == 0) {
      v = skip[(size_t)bs * Cs + cc];
    } else {
      if (cc < 16) v = cls[(size_t)b * 16 + cc];
      else if (cc < 19) v = xyz[(size_t)bs * 3 + (cc - 16)];
      else v = nrm[(size_t)bs * 3 + (cc - 19)];
    }
  }
  cat[g] = v;
}

// ---------------- transpose g0 [B,N,128] -> out2 [B,128,N] ----------------
__global__ __launch_bounds__(256) void transpose_g0_kernel(const float* __restrict__ g0,
                                                           float* __restrict__ out2) {
  __shared__ float tile[32][33];
  int n0 = blockIdx.x * 32, c0 = blockIdx.y * 32, b = blockIdx.z;
  int tx = threadIdx.x & 31, ty = threadIdx.x >> 5;  // ty 0..7
#pragma unroll
  for (int j = 0; j < 32; j += 8)
    tile[ty + j][tx] = g0[((size_t)b * NPTS + n0 + ty + j) * 128 + c0 + tx];
  __syncthreads();
#pragma unroll
  for (int j = 0; j < 32; j += 8)
    out2[((size_t)b * 128 + c0 + ty + j) * NPTS + n0 + tx] = tile[tx][ty + j];
}

// ---------------- host-side orchestration ----------------
static inline int cdiv(int a, int b) { return (a + b - 1) / b; }

extern "C" void kernel_launch(void* const* d_in, const int* in_sizes, int n_in,
                              void* d_out, int out_size, void* d_ws, size_t ws_size,
                              hipStream_t stream) {
  const float* x    = (const float*)d_in[0];
  const float* cls  = (const float*)d_in[1];
  const float* W0 = (const float*)d_in[2];  const float* b0 = (const float*)d_in[3];
  const float* W1 = (const float*)d_in[4];  const float* b1 = (const float*)d_in[5];
  const float* W2 = (const float*)d_in[6];  const float* b2 = (const float*)d_in[7];
  const float* W3 = (const float*)d_in[8];  const float* b3 = (const float*)d_in[9];
  const float* F3 = (const float*)d_in[10]; const float* fb3 = (const float*)d_in[11];
  const float* F2 = (const float*)d_in[12]; const float* fb2 = (const float*)d_in[13];
  const float* F1 = (const float*)d_in[14]; const float* fb1 = (const float*)d_in[15];
  const float* F0 = (const float*)d_in[16]; const float* fb0 = (const float*)d_in[17];
  const float* Wseg = (const float*)d_in[18]; const float* bseg = (const float*)d_in[19];
  float* out = (float*)d_out;

  float* ws = (float*)d_ws;
  size_t off = 0;
  auto alloc = [&](size_t n) { float* p = ws + off; off += (n + 3) & ~(size_t)3; return p; };
  float* xyz = alloc(8 * 4096 * 3);
  float* nrm = alloc(8 * 4096 * 3);
  float* x1 = alloc(8 * 512 * 3);  float* f1 = alloc(8 * 512 * 64);
  float* x2 = alloc(8 * 256 * 3);  float* f2 = alloc(8 * 256 * 128);
  float* x3 = alloc(8 * 128 * 3);  float* f3 = alloc(8 * 128 * 256);
  float* x4 = alloc(8 * 64 * 3);   float* f4 = alloc(8 * 64 * 512);
  float* g3 = alloc(8 * 128 * 512);
  float* g2 = alloc(8 * 256 * 256);
  float* g1 = alloc(8 * 512 * 128);
  float* g0 = alloc(8 * 4096 * 128);
  float* w3buf = alloc(8 * 4096 * 3);
  float* grpbuf = alloc(8 * 4096 * 150);       // grp / cat scratch
  float* Hbuf = alloc(8 * 512 * 20 * 64);      // H scratch
  int* nidx = (int*)alloc(8 * 512 * 20);
  int* idx3 = (int*)alloc(8 * 4096 * 3);

  // 0. split/transpose input
  split_xyz_kernel<<<cdiv(8 * 4096, 256), 256, 0, stream>>>(x, xyz, nrm);

  // ---- SA1: 4096 -> 512, C 3 -> 64 (Cin 6) ----
  fps4_kernel<512, 8><<<8, 512, 0, stream>>>(xyz, 4096, 512, x1);
  knn20_kernel<<<8 * 512, 64, 0, stream>>>(x1, xyz, 512, 4096, nidx);
  {
    int total = 8 * 512 * 20 * 6;
    group_kernel<<<cdiv(total, 256), 256, 0, stream>>>(xyz, nrm, x1, nidx, 4096, 512, 3, grpbuf, total);
    dim3 grid(cdiv(64, 64), cdiv(8 * 512 * 20, 64));
    gemm_kernel<<<grid, 256, 0, stream>>>(grpbuf, W0, b0, Hbuf, 8 * 512 * 20, 64, 6, 1);
    int tp = 8 * 512 * 64;
    maxpool_kernel<<<cdiv(tp, 256), 256, 0, stream>>>(Hbuf, 8 * 512, 64, f1);
  }

  // ---- SA2: 512 -> 256, C 64 -> 128 (Cin 67) ----
  fps4_kernel<512, 1><<<8, 512, 0, stream>>>(x1, 512, 256, x2);
  knn20_kernel<<<8 * 256, 64, 0, stream>>>(x2, x1, 256, 512, nidx);
  {
    int total = 8 * 256 * 20 * 67;
    group_kernel<<<cdiv(total, 256), 256, 0, stream>>>(x1, f1, x2, nidx, 512, 256, 64, grpbuf, total);
    dim3 grid(cdiv(128, 64), cdiv(8 * 256 * 20, 64));
    gemm_kernel<<<grid, 256, 0, stream>>>(grpbuf, W1, b1, Hbuf, 8 * 256 * 20, 128, 67, 1);
    int tp = 8 * 256 * 128;
    maxpool_kernel<<<cdiv(tp, 256), 256, 0, stream>>>(Hbuf, 8 * 256, 128, f2);
  }

  // ---- SA3: 256 -> 128, C 128 -> 256 (Cin 131) ----
  fps4_kernel<256, 1><<<8, 256, 0, stream>>>(x2, 256, 128, x3);
  knn20_kernel<<<8 * 128, 64, 0, stream>>>(x3, x2, 128, 256, nidx);
  {
    int total = 8 * 128 * 20 * 131;
    group_kernel<<<cdiv(total, 256), 256, 0, stream>>>(x2, f2, x3, nidx, 256, 128, 128, grpbuf, total);
    dim3 grid(cdiv(256, 64), cdiv(8 * 128 * 20, 64));
    gemm_kernel<<<grid, 256, 0, stream>>>(grpbuf, W2, b2, Hbuf, 8 * 128 * 20, 256, 131, 1);
    int tp = 8 * 128 * 256;
    maxpool_kernel<<<cdiv(tp, 256), 256, 0, stream>>>(Hbuf, 8 * 128, 256, f3);
  }

  // ---- SA4: 128 -> 64, C 256 -> 512 (Cin 259) ----
  fps4_kernel<128, 1><<<8, 128, 0, stream>>>(x3, 128, 64, x4);
  knn20_kernel<<<8 * 64, 64, 0, stream>>>(x4, x3, 64, 128, nidx);
  {
    int total = 8 * 64 * 20 * 259;
    group_kernel<<<cdiv(total, 256), 256, 0, stream>>>(x3, f3, x4, nidx, 128, 64, 256, grpbuf, total);
    dim3 grid(cdiv(512, 64), cdiv(8 * 64 * 20, 64));
    gemm_kernel<<<grid, 256, 0, stream>>>(grpbuf, W3, b3, Hbuf, 8 * 64 * 20, 512, 259, 1);
    int tp = 8 * 64 * 512;
    maxpool_kernel<<<cdiv(tp, 256), 256, 0, stream>>>(Hbuf, 8 * 64, 512, f4);
  }

  // ---- FP3: interp f4 (x4->x3) + skip f3 -> g3 [B,128,512] ----
  knn3_kernel<<<cdiv(8 * 128, 256), 256, 0, stream>>>(x3, x4, 128, 64, idx3, w3buf, 8 * 128);
  {
    int total = 8 * 128 * 768;
    fp_cat_kernel<<<cdiv(total, 256), 256, 0, stream>>>(f4, idx3, w3buf, f3, nullptr, nullptr, nullptr,
                                                        128, 64, 512, 256, 0, grpbuf, total);
    dim3 grid(cdiv(512, 64), cdiv(8 * 128, 64));
    gemm_kernel<<<grid, 256, 0, stream>>>(grpbuf, F3, fb3, g3, 8 * 128, 512, 768, 1);
  }

  // ---- FP2: interp g3 (x3->x2) + skip f2 -> g2 [B,256,256] ----
  knn3_kernel<<<cdiv(8 * 256, 256), 256, 0, stream>>>(x2, x3, 256, 128, idx3, w3buf, 8 * 256);
  {
    int total = 8 * 256 * 640;
    fp_cat_kernel<<<cdiv(total, 256), 256, 0, stream>>>(g3, idx3, w3buf, f2, nullptr, nullptr, nullptr,
                                                        256, 128, 512, 128, 0, grpbuf, total);
    dim3 grid(cdiv(256, 64), cdiv(8 * 256, 64));
    gemm_kernel<<<grid, 256, 0, stream>>>(grpbuf, F2, fb2, g2, 8 * 256, 256, 640, 1);
  }

  // ---- FP1: interp g2 (x2->x1) + skip f1 -> g1 [B,512,128] ----
  knn3_kernel<<<cdiv(8 * 512, 256), 256, 0, stream>>>(x1, x2, 512, 256, idx3, w3buf, 8 * 512);
  {
    int total = 8 * 512 * 320;
    fp_cat_kernel<<<cdiv(total, 256), 256, 0, stream>>>(g2, idx3, w3buf, f1, nullptr, nullptr, nullptr,
                                                        512, 256, 256, 64, 0, grpbuf, total);
    dim3 grid(cdiv(128, 64), cdiv(8 * 512, 64));
    gemm_kernel<<<grid, 256, 0, stream>>>(grpbuf, F1, fb1, g1, 8 * 512, 128, 320, 1);
  }

  // ---- FP0: interp g1 (x1->xyz) + skip [cls,xyz,nrm] -> g0 [B,4096,128] ----
  knn3_kernel<<<cdiv(8 * 4096, 256), 256, 0, stream>>>(xyz, x1, 4096, 512, idx3, w3buf, 8 * 4096);
  {
    int total = 8 * 4096 * 150;
    fp_cat_kernel<<<cdiv(total, 256), 256, 0, stream>>>(g1, idx3, w3buf, nullptr, cls, xyz, nrm,
                                                        4096, 512, 128, 22, 1, grpbuf, total);
    dim3 grid(cdiv(128, 64), cdiv(8 * 4096, 64));
    gemm_kernel<<<grid, 256, 0, stream>>>(grpbuf, F0, fb0, g0, 8 * 4096, 128, 150, 1);
  }

  // ---- seg head: out1 = g0 @ Wseg + bseg (no relu) ----
  {
    dim3 grid(cdiv(50, 64), cdiv(8 * 4096, 64));
    gemm_kernel<<<grid, 256, 0, stream>>>(g0, Wseg, bseg, out, 8 * 4096, 50, 128, 0);
  }
  // ---- out2 = transpose(g0) ----
  transpose_g0_kernel<<<dim3(128, 4, 8), 256, 0, stream>>>(g0, out + (size_t)8 * 4096 * 50);
}

// Round 5
// 1531.915 us; speedup vs baseline: 1.5090x; 1.1273x over previous
//
#include <hip/hip_runtime.h>
#include <float.h>

#define B8 8
#define NPTS 4096

// ---------------- split x[B,6,N] -> xyz[B,N,3], nrm[B,N,3] ----------------
__global__ void split_xyz_kernel(const float* __restrict__ x,
                                 float* __restrict__ xyz, float* __restrict__ nrm) {
  int g = blockIdx.x * 256 + threadIdx.x;
  if (g >= B8 * NPTS) return;
  int b = g / NPTS, n = g % NPTS;
  const float* xb = x + (size_t)b * 6 * NPTS;
  float* o1 = xyz + (size_t)g * 3;
  float* o2 = nrm + (size_t)g * 3;
  o1[0] = xb[0 * NPTS + n]; o1[1] = xb[1 * NPTS + n]; o1[2] = xb[2 * NPTS + n];
  o2[0] = xb[3 * NPTS + n]; o2[1] = xb[4 * NPTS + n]; o2[2] = xb[5 * NPTS + n];
}

// ---------------- DPP helpers (register-only cross-lane) ----------------
template <int CTRL, int RM>
__device__ __forceinline__ unsigned dppmov(unsigned v) {
  return (unsigned)__builtin_amdgcn_update_dpp((int)v, (int)v, CTRL, RM, 0xf, false);
}

template <int CTRL, int RM>
__device__ __forceinline__ void red_key_max(unsigned& kh, unsigned& kl) {
  unsigned oh = dppmov<CTRL, RM>(kh);
  unsigned ol = dppmov<CTRL, RM>(kl);
  unsigned long long ko = ((unsigned long long)oh << 32) | ol;
  unsigned long long k  = ((unsigned long long)kh << 32) | kl;
  bool c = ko > k;
  kh = c ? oh : kh;
  kl = c ? ol : kl;
}

template <int CTRL, int RM>
__device__ __forceinline__ void red_key_min(unsigned& kh, unsigned& kl) {
  unsigned oh = dppmov<CTRL, RM>(kh);
  unsigned ol = dppmov<CTRL, RM>(kl);
  unsigned long long ko = ((unsigned long long)oh << 32) | ol;
  unsigned long long k  = ((unsigned long long)kh << 32) | kl;
  bool c = ko < k;
  kh = c ? oh : kh;
  kl = c ? ol : kl;
}

#define WAVE_RED_MAX(kh, kl)            \
  red_key_max<0x111, 0xf>(kh, kl);      \
  red_key_max<0x112, 0xf>(kh, kl);      \
  red_key_max<0x114, 0xf>(kh, kl);      \
  red_key_max<0x118, 0xf>(kh, kl);      \
  red_key_max<0x142, 0xa>(kh, kl);      \
  red_key_max<0x143, 0xc>(kh, kl);

#define WAVE_RED_MIN(kh, kl)            \
  red_key_min<0x111, 0xf>(kh, kl);      \
  red_key_min<0x112, 0xf>(kh, kl);      \
  red_key_min<0x114, 0xf>(kh, kl);      \
  red_key_min<0x118, 0xf>(kh, kl);      \
  red_key_min<0x142, 0xa>(kh, kl);      \
  red_key_min<0x143, 0xc>(kh, kl);

// ---------------- FPS, multi-wave (SA1) ----------------
// One block per batch, BLOCK*P == N. Key = (bits(dist)<<32)|~idx -> u64 max ==
// argmax with tie->lowest index. DPP wave reduce -> lane63 LDS key -> barrier ->
// redundant NW-key reduce (b128 broadcast reads) -> coord via ds_read_b128.
template <int BLOCK, int P>
__global__ __launch_bounds__(BLOCK) void fps4_kernel(const float* __restrict__ xyz,
                                                     int N, int S,
                                                     float* __restrict__ out_xyz) {
#pragma clang fp contract(off)
  constexpr int NW = BLOCK / 64;
  __shared__ float4 pts[BLOCK * P];
  __shared__ alignas(16) unsigned long long wkey[2][NW];
  int b = blockIdx.x, t = threadIdx.x;
  const float* p = xyz + (size_t)b * N * 3;
  float px[P], py[P], pz[P], dist[P];
#pragma unroll
  for (int j = 0; j < P; ++j) {
    int idx = t + j * BLOCK;
    float a = p[3 * idx], bb = p[3 * idx + 1], c = p[3 * idx + 2];
    px[j] = a; py[j] = bb; pz[j] = c;
    pts[idx] = make_float4(a, bb, c, 0.f);
    dist[j] = 1e10f;
  }
  __syncthreads();
  float fx = p[0], fy = p[1], fz = p[2];
  for (int i = 0; i < S; ++i) {
    if (t == 0) {
      float* o = out_xyz + ((size_t)b * S + i) * 3;
      o[0] = fx; o[1] = fy; o[2] = fz;
    }
    unsigned long long best = 0ull;
#pragma unroll
    for (int j = 0; j < P; ++j) {
      int idx = t + j * BLOCK;
      float dx = px[j] - fx, dy = py[j] - fy, dz = pz[j] - fz;
      float d = dx * dx + dy * dy + dz * dz;
      float nd = fminf(dist[j], d);
      dist[j] = nd;
      unsigned long long key =
          ((unsigned long long)__float_as_uint(nd) << 32) | (unsigned)(~idx);
      best = (key > best) ? key : best;
    }
    unsigned kh = (unsigned)(best >> 32), kl = (unsigned)best;
    WAVE_RED_MAX(kh, kl);
    int buf = i & 1;
    if ((t & 63) == 63)
      wkey[buf][t >> 6] = ((unsigned long long)kh << 32) | kl;
    __syncthreads();
    unsigned long long g = 0ull;
    const ulonglong2* wk2 = (const ulonglong2*)&wkey[buf][0];
#pragma unroll
    for (int w = 0; w < NW / 2; ++w) {
      ulonglong2 e = wk2[w];
      unsigned long long m = (e.x > e.y) ? e.x : e.y;
      g = (m > g) ? m : g;
    }
    int far = (int)~(unsigned)g;
    float4 f = pts[far];
    fx = f.x; fy = f.y; fz = f.z;
  }
}

// ---------------- FPS, single-wave (SA2..SA4): no barriers in the loop ----------------
template <int P>
__global__ __launch_bounds__(64) void fps_wave_kernel(const float* __restrict__ xyz,
                                                      int N, int S,
                                                      float* __restrict__ out_xyz) {
#pragma clang fp contract(off)
  __shared__ float4 pts[64 * P];
  int b = blockIdx.x, t = threadIdx.x;
  const float* p = xyz + (size_t)b * N * 3;
  float px[P], py[P], pz[P], dist[P];
#pragma unroll
  for (int j = 0; j < P; ++j) {
    int idx = t + j * 64;
    float a = p[3 * idx], bb = p[3 * idx + 1], c = p[3 * idx + 2];
    px[j] = a; py[j] = bb; pz[j] = c;
    pts[idx] = make_float4(a, bb, c, 0.f);
    dist[j] = 1e10f;
  }
  __syncthreads();
  float fx = p[0], fy = p[1], fz = p[2];
  for (int i = 0; i < S; ++i) {
    if (t == 0) {
      float* o = out_xyz + ((size_t)b * S + i) * 3;
      o[0] = fx; o[1] = fy; o[2] = fz;
    }
    unsigned long long best = 0ull;
#pragma unroll
    for (int j = 0; j < P; ++j) {
      int idx = t + j * 64;
      float dx = px[j] - fx, dy = py[j] - fy, dz = pz[j] - fz;
      float d = dx * dx + dy * dy + dz * dz;
      float nd = fminf(dist[j], d);
      dist[j] = nd;
      unsigned long long key =
          ((unsigned long long)__float_as_uint(nd) << 32) | (unsigned)(~idx);
      best = (key > best) ? key : best;
    }
    unsigned kh = (unsigned)(best >> 32), kl = (unsigned)best;
    WAVE_RED_MAX(kh, kl);
    unsigned gl = (unsigned)__builtin_amdgcn_readlane((int)kl, 63);
    int far = (int)~gl;
    float4 f = pts[far];
    fx = f.x; fy = f.y; fz = f.z;
  }
}

// ---------------- kNN k=20: one wave/query, u64-min-key DPP argmin ----------------
__global__ __launch_bounds__(64) void knn20_kernel(const float* __restrict__ q,
                                                   const float* __restrict__ ref,
                                                   int S, int M, int* __restrict__ nidx) {
#pragma clang fp contract(off)
  int bs = blockIdx.x;
  int b = bs / S;
  int t = threadIdx.x;
  __shared__ float sd[4096];
  const float* qp = q + (size_t)bs * 3;
  float qx = qp[0], qy = qp[1], qz = qp[2];
  float qq = qx * qx + qy * qy + qz * qz;
  const float* rp = ref + (size_t)b * M * 3;
  for (int i = t; i < M; i += 64) {
    float rx = rp[3 * i], ry = rp[3 * i + 1], rz = rp[3 * i + 2];
    float rr = rx * rx + ry * ry + rz * rz;
    float dot = qx * rx + qy * ry + qz * rz;
    sd[i] = qq - 2.0f * dot + rr;
  }
  __syncthreads();
  int* out = nidx + (size_t)bs * 20;
  for (int k = 0; k < 20; ++k) {
    unsigned long long best = ~0ull;
    for (int i = t; i < M; i += 64) {
      unsigned long long key =
          ((unsigned long long)__float_as_uint(sd[i]) << 32) | (unsigned)i;
      best = (key < best) ? key : best;
    }
    unsigned kh = (unsigned)(best >> 32), kl = (unsigned)best;
    WAVE_RED_MIN(kh, kl);
    int bi = (int)(unsigned)__builtin_amdgcn_readlane((int)kl, 63);
    if (t == 0) { out[k] = bi; sd[bi] = FLT_MAX; }
    __syncthreads();
  }
}

// ---------------- GEMM core macro pieces ----------------
// As padded to [16][68]: staging-write bank (4*kk+m)%32 -> 2-way max (free);
// rows are 272 B so float4 reads stay 16B-aligned.
#define GEMM_BODY(AS_EXPR)                                                        \
  __shared__ alignas(16) float As[16][68];                                        \
  __shared__ float Bs[16][64];                                                    \
  int tx = threadIdx.x & 15, ty = threadIdx.x >> 4;                               \
  int rowBase = blockIdx.y * 64;                                                  \
  int colBase = blockIdx.x * 64;                                                  \
  float acc[4][4] = {};                                                           \
  for (int k0 = 0; k0 < K; k0 += 16) {                                            \
    for (int l = threadIdx.x; l < 1024; l += 256) {                               \
      int m = l >> 4, kk = l & 15;                                                \
      int rr = rowBase + m, kq = k0 + kk;                                         \
      float v = 0.0f;                                                             \
      if (rr < Mrows && kq < K) { AS_EXPR }                                       \
      As[kk][m] = v;                                                              \
    }                                                                             \
    for (int l = threadIdx.x; l < 1024; l += 256) {                               \
      int kk = l >> 6, n = l & 63;                                                \
      int kq = k0 + kk, cc = colBase + n;                                         \
      Bs[kk][n] = (kq < K && cc < N) ? Wm[(size_t)kq * N + cc] : 0.0f;            \
    }                                                                             \
    __syncthreads();                                                              \
    _Pragma("unroll")                                                             \
    for (int kk = 0; kk < 16; ++kk) {                                             \
      const float4 av = *reinterpret_cast<const float4*>(&As[kk][ty * 4]);        \
      const float4 bv = *reinterpret_cast<const float4*>(&Bs[kk][tx * 4]);        \
      acc[0][0] += av.x * bv.x; acc[0][1] += av.x * bv.y;                         \
      acc[0][2] += av.x * bv.z; acc[0][3] += av.x * bv.w;                         \
      acc[1][0] += av.y * bv.x; acc[1][1] += av.y * bv.y;                         \
      acc[1][2] += av.y * bv.z; acc[1][3] += av.y * bv.w;                         \
      acc[2][0] += av.z * bv.x; acc[2][1] += av.z * bv.y;                         \
      acc[2][2] += av.z * bv.z; acc[2][3] += av.z * bv.w;                         \
      acc[3][0] += av.w * bv.x; acc[3][1] += av.w * bv.y;                         \
      acc[3][2] += av.w * bv.z; acc[3][3] += av.w * bv.w;                         \
    }                                                                             \
    __syncthreads();                                                              \
  }                                                                               \
  _Pragma("unroll")                                                               \
  for (int i = 0; i < 4; ++i) {                                                   \
    int row = rowBase + ty * 4 + i;                                               \
    if (row >= Mrows) continue;                                                   \
    _Pragma("unroll")                                                             \
    for (int j = 0; j < 4; ++j) {                                                 \
      int col = colBase + tx * 4 + j;                                             \
      if (col >= N) continue;                                                     \
      float v = acc[i][j] + bias[col];                                            \
      if (RELU) v = fmaxf(v, 0.0f);                                               \
      C[(size_t)row * N + col] = v;                                               \
    }                                                                             \
  }

// plain GEMM (seg head)
__global__ __launch_bounds__(256) void gemm_kernel(const float* __restrict__ A,
                                                   const float* __restrict__ Wm,
                                                   const float* __restrict__ bias,
                                                   float* __restrict__ C,
                                                   int Mrows, int N, int K, int RELU) {
  GEMM_BODY( v = A[(size_t)rr * K + kq]; )
}

// SA GEMM with fused grouping gather: row rr -> (b,s,k20) via nidx
__global__ __launch_bounds__(256) void gemm_sa_kernel(
    const float* __restrict__ xyz, const float* __restrict__ feats,
    const float* __restrict__ new_xyz, const int* __restrict__ nidx,
    const float* __restrict__ Wm, const float* __restrict__ bias,
    float* __restrict__ C, int Mref, int S, int Cf,
    int Mrows, int N, int K) {
  const int RELU = 1;
  GEMM_BODY(
    int bs = rr / 20;
    int b = bs / S;
    int id = nidx[rr];
    if (kq < 3)
      v = xyz[((size_t)b * Mref + id) * 3 + kq] - new_xyz[(size_t)bs * 3 + kq];
    else
      v = feats[((size_t)b * Mref + id) * Cf + (kq - 3)];
  )
}

// FP GEMM with fused 3-NN interp + skip concat: row rr -> bs
__global__ __launch_bounds__(256) void gemm_fp_kernel(
    const float* __restrict__ fr, const int* __restrict__ idx3,
    const float* __restrict__ w3, const float* __restrict__ skip,
    const float* __restrict__ cls, const float* __restrict__ xyzq,
    const float* __restrict__ nrmq,
    const float* __restrict__ Wm, const float* __restrict__ bias,
    float* __restrict__ C, int Sq, int Mr, int Cr, int Cs, int mode,
    int Mrows, int N, int K) {
  const int RELU = 1;
  GEMM_BODY(
    int bs = rr;
    int b = bs / Sq;
    if (kq < Cr) {
      const int* ii = idx3 + (size_t)bs * 3;
      const float* ww = w3 + (size_t)bs * 3;
      const float* fb = fr + (size_t)b * Mr * Cr;
      v = ww[0] * fb[(size_t)ii[0] * Cr + kq];
      v += ww[1] * fb[(size_t)ii[1] * Cr + kq];
      v += ww[2] * fb[(size_t)ii[2] * Cr + kq];
    } else {
      int cc = kq - Cr;
      if (mode == 0) {
        v = skip[(size_t)bs * Cs + cc];
      } else {
        if (cc < 16) v = cls[(size_t)b * 16 + cc];
        else if (cc < 19) v = xyzq[(size_t)bs * 3 + (cc - 16)];
        else v = nrmq[(size_t)bs * 3 + (cc - 19)];
      }
    }
  )
}

// ---------------- maxpool over K=20 neighbors ----------------
__global__ void maxpool_kernel(const float* __restrict__ H, int SB, int C,
                               float* __restrict__ f) {
  int g = blockIdx.x * 256 + threadIdx.x;
  if (g >= SB * C) return;
  int d = g % C;
  int bs = g / C;
  const float* h = H + (size_t)bs * 20 * C + d;
  float m = h[0];
#pragma unroll
  for (int k = 1; k < 20; ++k) m = fmaxf(m, h[(size_t)k * C]);
  f[g] = m;
}

// ---------------- kNN k=3 + inverse-distance weights (one thread per query) ----------------
__global__ void knn3_kernel(const float* __restrict__ q, const float* __restrict__ ref,
                            int Sq, int M, int* __restrict__ idx3, float* __restrict__ w3,
                            int total) {
#pragma clang fp contract(off)
  int g = blockIdx.x * 256 + threadIdx.x;
  if (g >= total) return;
  int b = g / Sq;
  const float* qp = q + (size_t)g * 3;
  float qx = qp[0], qy = qp[1], qz = qp[2];
  float qq = qx * qx + qy * qy + qz * qz;
  const float* rp = ref + (size_t)b * M * 3;
  float v0 = FLT_MAX, v1 = FLT_MAX, v2 = FLT_MAX;
  int i0 = 0, i1 = 0, i2 = 0;
  for (int i = 0; i < M; ++i) {
    float rx = rp[3 * i], ry = rp[3 * i + 1], rz = rp[3 * i + 2];
    float d = qq - 2.0f * (qx * rx + qy * ry + qz * rz) + (rx * rx + ry * ry + rz * rz);
    if (d < v2) {
      if (d < v1) {
        if (d < v0) { v2 = v1; i2 = i1; v1 = v0; i1 = i0; v0 = d; i0 = i; }
        else { v2 = v1; i2 = i1; v1 = d; i1 = i; }
      } else { v2 = d; i2 = i; }
    }
  }
  int ii[3] = {i0, i1, i2};
  float w[3];
  float wsum = 0.0f;
#pragma unroll
  for (int k = 0; k < 3; ++k) {
    const float* r = rp + (size_t)ii[k] * 3;
    float dx = r[0] - qx, dy = r[1] - qy, dz = r[2] - qz;
    float d = dx * dx + dy * dy + dz * dz;
    w[k] = 1.0f / (d + 1e-8f);
    wsum += w[k];
  }
#pragma unroll
  for (int k = 0; k < 3; ++k) {
    idx3[(size_t)g * 3 + k] = ii[k];
    w3[(size_t)g * 3 + k] = w[k] / wsum;
  }
}

// ---------------- transpose g0 [B,N,128] -> out2 [B,128,N] ----------------
__global__ __launch_bounds__(256) void transpose_g0_kernel(const float* __restrict__ g0,
                                                           float* __restrict__ out2) {
  __shared__ float tile[32][33];
  int n0 = blockIdx.x * 32, c0 = blockIdx.y * 32, b = blockIdx.z;
  int tx = threadIdx.x & 31, ty = threadIdx.x >> 5;  // ty 0..7
#pragma unroll
  for (int j = 0; j < 32; j += 8)
    tile[ty + j][tx] = g0[((size_t)b * NPTS + n0 + ty + j) * 128 + c0 + tx];
  __syncthreads();
#pragma unroll
  for (int j = 0; j < 32; j += 8)
    out2[((size_t)b * 128 + c0 + ty + j) * NPTS + n0 + tx] = tile[tx][ty + j];
}

// ---------------- host-side orchestration ----------------
static inline int cdiv(int a, int b) { return (a + b - 1) / b; }

extern "C" void kernel_launch(void* const* d_in, const int* in_sizes, int n_in,
                              void* d_out, int out_size, void* d_ws, size_t ws_size,
                              hipStream_t stream) {
  const float* x    = (const float*)d_in[0];
  const float* cls  = (const float*)d_in[1];
  const float* W0 = (const float*)d_in[2];  const float* b0 = (const float*)d_in[3];
  const float* W1 = (const float*)d_in[4];  const float* b1 = (const float*)d_in[5];
  const float* W2 = (const float*)d_in[6];  const float* b2 = (const float*)d_in[7];
  const float* W3 = (const float*)d_in[8];  const float* b3 = (const float*)d_in[9];
  const float* F3 = (const float*)d_in[10]; const float* fb3 = (const float*)d_in[11];
  const float* F2 = (const float*)d_in[12]; const float* fb2 = (const float*)d_in[13];
  const float* F1 = (const float*)d_in[14]; const float* fb1 = (const float*)d_in[15];
  const float* F0 = (const float*)d_in[16]; const float* fb0 = (const float*)d_in[17];
  const float* Wseg = (const float*)d_in[18]; const float* bseg = (const float*)d_in[19];
  float* out = (float*)d_out;

  float* ws = (float*)d_ws;
  size_t off = 0;
  auto alloc = [&](size_t n) { float* p = ws + off; off += (n + 3) & ~(size_t)3; return p; };
  float* xyz = alloc(8 * 4096 * 3);
  float* nrm = alloc(8 * 4096 * 3);
  float* x1 = alloc(8 * 512 * 3);  float* f1 = alloc(8 * 512 * 64);
  float* x2 = alloc(8 * 256 * 3);  float* f2 = alloc(8 * 256 * 128);
  float* x3 = alloc(8 * 128 * 3);  float* f3 = alloc(8 * 128 * 256);
  float* x4 = alloc(8 * 64 * 3);   float* f4 = alloc(8 * 64 * 512);
  float* g3 = alloc(8 * 128 * 512);
  float* g2 = alloc(8 * 256 * 256);
  float* g1 = alloc(8 * 512 * 128);
  float* g0 = alloc(8 * 4096 * 128);
  float* w3buf = alloc(8 * 4096 * 3);
  float* Hbuf = alloc(8 * 512 * 20 * 64);      // SA hidden scratch (5.24M floats max)
  int* nidx = (int*)alloc(8 * 512 * 20);
  int* idx3 = (int*)alloc(8 * 4096 * 3);

  // 0. split/transpose input
  split_xyz_kernel<<<cdiv(8 * 4096, 256), 256, 0, stream>>>(x, xyz, nrm);

  // ---- SA1: 4096 -> 512, C 3 -> 64 (Cin 6) ----
  fps4_kernel<256, 16><<<8, 256, 0, stream>>>(xyz, 4096, 512, x1);
  knn20_kernel<<<8 * 512, 64, 0, stream>>>(x1, xyz, 512, 4096, nidx);
  {
    dim3 grid(1, cdiv(8 * 512 * 20, 64));
    gemm_sa_kernel<<<grid, 256, 0, stream>>>(xyz, nrm, x1, nidx, W0, b0, Hbuf,
                                             4096, 512, 3, 8 * 512 * 20, 64, 6);
    maxpool_kernel<<<cdiv(8 * 512 * 64, 256), 256, 0, stream>>>(Hbuf, 8 * 512, 64, f1);
  }

  // ---- SA2: 512 -> 256, C 64 -> 128 (Cin 67) ----
  fps_wave_kernel<8><<<8, 64, 0, stream>>>(x1, 512, 256, x2);
  knn20_kernel<<<8 * 256, 64, 0, stream>>>(x2, x1, 256, 512, nidx);
  {
    dim3 grid(2, cdiv(8 * 256 * 20, 64));
    gemm_sa_kernel<<<grid, 256, 0, stream>>>(x1, f1, x2, nidx, W1, b1, Hbuf,
                                             512, 256, 64, 8 * 256 * 20, 128, 67);
    maxpool_kernel<<<cdiv(8 * 256 * 128, 256), 256, 0, stream>>>(Hbuf, 8 * 256, 128, f2);
  }

  // ---- SA3: 256 -> 128, C 128 -> 256 (Cin 131) ----
  fps_wave_kernel<4><<<8, 64, 0, stream>>>(x2, 256, 128, x3);
  knn20_kernel<<<8 * 128, 64, 0, stream>>>(x3, x2, 128, 256, nidx);
  {
    dim3 grid(4, cdiv(8 * 128 * 20, 64));
    gemm_sa_kernel<<<grid, 256, 0, stream>>>(x2, f2, x3, nidx, W2, b2, Hbuf,
                                             256, 128, 128, 8 * 128 * 20, 256, 131);
    maxpool_kernel<<<cdiv(8 * 128 * 256, 256), 256, 0, stream>>>(Hbuf, 8 * 128, 256, f3);
  }

  // ---- SA4: 128 -> 64, C 256 -> 512 (Cin 259) ----
  fps_wave_kernel<2><<<8, 64, 0, stream>>>(x3, 128, 64, x4);
  knn20_kernel<<<8 * 64, 64, 0, stream>>>(x4, x3, 64, 128, nidx);
  {
    dim3 grid(8, cdiv(8 * 64 * 20, 64));
    gemm_sa_kernel<<<grid, 256, 0, stream>>>(x3, f3, x4, nidx, W3, b3, Hbuf,
                                             128, 64, 256, 8 * 64 * 20, 512, 259);
    maxpool_kernel<<<cdiv(8 * 64 * 512, 256), 256, 0, stream>>>(Hbuf, 8 * 64, 512, f4);
  }

  // ---- FP3: interp f4 (x4->x3) + skip f3 -> g3 [B,128,512] ----
  knn3_kernel<<<cdiv(8 * 128, 256), 256, 0, stream>>>(x3, x4, 128, 64, idx3, w3buf, 8 * 128);
  {
    dim3 grid(8, cdiv(8 * 128, 64));
    gemm_fp_kernel<<<grid, 256, 0, stream>>>(f4, idx3, w3buf, f3, nullptr, nullptr, nullptr,
                                             F3, fb3, g3, 128, 64, 512, 256, 0,
                                             8 * 128, 512, 768);
  }

  // ---- FP2: interp g3 (x3->x2) + skip f2 -> g2 [B,256,256] ----
  knn3_kernel<<<cdiv(8 * 256, 256), 256, 0, stream>>>(x2, x3, 256, 128, idx3, w3buf, 8 * 256);
  {
    dim3 grid(4, cdiv(8 * 256, 64));
    gemm_fp_kernel<<<grid, 256, 0, stream>>>(g3, idx3, w3buf, f2, nullptr, nullptr, nullptr,
                                             F2, fb2, g2, 256, 128, 512, 128, 0,
                                             8 * 256, 256, 640);
  }

  // ---- FP1: interp g2 (x2->x1) + skip f1 -> g1 [B,512,128] ----
  knn3_kernel<<<cdiv(8 * 512, 256), 256, 0, stream>>>(x1, x2, 512, 256, idx3, w3buf, 8 * 512);
  {
    dim3 grid(2, cdiv(8 * 512, 64));
    gemm_fp_kernel<<<grid, 256, 0, stream>>>(g2, idx3, w3buf, f1, nullptr, nullptr, nullptr,
                                             F1, fb1, g1, 512, 256, 256, 64, 0,
                                             8 * 512, 128, 320);
  }

  // ---- FP0: interp g1 (x1->xyz) + skip [cls,xyz,nrm] -> g0 [B,4096,128] ----
  knn3_kernel<<<cdiv(8 * 4096, 256), 256, 0, stream>>>(xyz, x1, 4096, 512, idx3, w3buf, 8 * 4096);
  {
    dim3 grid(2, cdiv(8 * 4096, 64));
    gemm_fp_kernel<<<grid, 256, 0, stream>>>(g1, idx3, w3buf, nullptr, cls, xyz, nrm,
                                             F0, fb0, g0, 4096, 512, 128, 22, 1,
                                             8 * 4096, 128, 150);
  }

  // ---- seg head: out1 = g0 @ Wseg + bseg (no relu) ----
  {
    dim3 grid(1, cdiv(8 * 4096, 64));
    gemm_kernel<<<grid, 256, 0, stream>>>(g0, Wseg, bseg, out, 8 * 4096, 50, 128, 0);
  }
  // ---- out2 = transpose(g0) ----
  transpose_g0_kernel<<<dim3(128, 4, 8), 256, 0, stream>>>(g0, out + (size_t)8 * 4096 * 50);
}

// Round 6
// 1384.573 us; speedup vs baseline: 1.6695x; 1.1064x over previous
//
#include <hip/hip_runtime.h>
#include <float.h>

#define B8 8
#define NPTS 4096

// ---------------- split x[B,6,N] -> xyz[B,N,3], nrm[B,N,3] ----------------
__global__ void split_xyz_kernel(const float* __restrict__ x,
                                 float* __restrict__ xyz, float* __restrict__ nrm) {
  int g = blockIdx.x * 256 + threadIdx.x;
  if (g >= B8 * NPTS) return;
  int b = g / NPTS, n = g % NPTS;
  const float* xb = x + (size_t)b * 6 * NPTS;
  float* o1 = xyz + (size_t)g * 3;
  float* o2 = nrm + (size_t)g * 3;
  o1[0] = xb[0 * NPTS + n]; o1[1] = xb[1 * NPTS + n]; o1[2] = xb[2 * NPTS + n];
  o2[0] = xb[3 * NPTS + n]; o2[1] = xb[4 * NPTS + n]; o2[2] = xb[5 * NPTS + n];
}

// ---------------- DPP helpers (register-only cross-lane) ----------------
template <int CTRL, int RM>
__device__ __forceinline__ unsigned dppmov(unsigned v) {
  return (unsigned)__builtin_amdgcn_update_dpp((int)v, (int)v, CTRL, RM, 0xf, false);
}

template <int CTRL, int RM>
__device__ __forceinline__ void red_key_max(unsigned& kh, unsigned& kl) {
  unsigned oh = dppmov<CTRL, RM>(kh);
  unsigned ol = dppmov<CTRL, RM>(kl);
  unsigned long long ko = ((unsigned long long)oh << 32) | ol;
  unsigned long long k  = ((unsigned long long)kh << 32) | kl;
  bool c = ko > k;
  kh = c ? oh : kh;
  kl = c ? ol : kl;
}

template <int CTRL, int RM>
__device__ __forceinline__ void red_key_min(unsigned& kh, unsigned& kl) {
  unsigned oh = dppmov<CTRL, RM>(kh);
  unsigned ol = dppmov<CTRL, RM>(kl);
  unsigned long long ko = ((unsigned long long)oh << 32) | ol;
  unsigned long long k  = ((unsigned long long)kh << 32) | kl;
  bool c = ko < k;
  kh = c ? oh : kh;
  kl = c ? ol : kl;
}

#define WAVE_RED_MAX(kh, kl)            \
  red_key_max<0x111, 0xf>(kh, kl);      \
  red_key_max<0x112, 0xf>(kh, kl);      \
  red_key_max<0x114, 0xf>(kh, kl);      \
  red_key_max<0x118, 0xf>(kh, kl);      \
  red_key_max<0x142, 0xa>(kh, kl);      \
  red_key_max<0x143, 0xc>(kh, kl);

#define WAVE_RED_MIN(kh, kl)            \
  red_key_min<0x111, 0xf>(kh, kl);      \
  red_key_min<0x112, 0xf>(kh, kl);      \
  red_key_min<0x114, 0xf>(kh, kl);      \
  red_key_min<0x118, 0xf>(kh, kl);      \
  red_key_min<0x142, 0xa>(kh, kl);      \
  red_key_min<0x143, 0xc>(kh, kl);

// ---------------- FPS (SA1 only; deeper levels are prefixes of x1) ----------------
// One block per batch, BLOCK*P == N. Key = (bits(dist)<<32)|~idx -> u64 max ==
// argmax with tie->lowest index. No global stores inside the loop: selected
// coords go to an LDS sel[] buffer (lgkm-only, so the per-iteration barrier
// never waits on vmcnt), written out cooperatively at the end.
template <int BLOCK, int P>
__global__ __launch_bounds__(BLOCK) void fps4_kernel(const float* __restrict__ xyz,
                                                     int N, int S,
                                                     float* __restrict__ out_xyz) {
#pragma clang fp contract(off)
  constexpr int NW = BLOCK / 64;
  __shared__ float4 pts[BLOCK * P];
  __shared__ float4 sel[512];
  __shared__ alignas(16) unsigned long long wkey[2][NW];
  int b = blockIdx.x, t = threadIdx.x;
  const float* p = xyz + (size_t)b * N * 3;
  float px[P], py[P], pz[P], dist[P];
#pragma unroll
  for (int j = 0; j < P; ++j) {
    int idx = t + j * BLOCK;
    float a = p[3 * idx], bb = p[3 * idx + 1], c = p[3 * idx + 2];
    px[j] = a; py[j] = bb; pz[j] = c;
    pts[idx] = make_float4(a, bb, c, 0.f);
    dist[j] = 1e10f;
  }
  __syncthreads();
  float fx = p[0], fy = p[1], fz = p[2];
  for (int i = 0; i < S; ++i) {
    if (t == 0) sel[i] = make_float4(fx, fy, fz, 0.f);
    unsigned long long best = 0ull;
#pragma unroll
    for (int j = 0; j < P; ++j) {
      int idx = t + j * BLOCK;
      float dx = px[j] - fx, dy = py[j] - fy, dz = pz[j] - fz;
      float d = dx * dx + dy * dy + dz * dz;
      float nd = fminf(dist[j], d);
      dist[j] = nd;
      unsigned long long key =
          ((unsigned long long)__float_as_uint(nd) << 32) | (unsigned)(~idx);
      best = (key > best) ? key : best;
    }
    unsigned kh = (unsigned)(best >> 32), kl = (unsigned)best;
    WAVE_RED_MAX(kh, kl);
    int buf = i & 1;
    if ((t & 63) == 63)
      wkey[buf][t >> 6] = ((unsigned long long)kh << 32) | kl;
    __syncthreads();
    unsigned long long g = 0ull;
    const ulonglong2* wk2 = (const ulonglong2*)&wkey[buf][0];
#pragma unroll
    for (int w = 0; w < NW / 2; ++w) {
      ulonglong2 e = wk2[w];
      unsigned long long m = (e.x > e.y) ? e.x : e.y;
      g = (m > g) ? m : g;
    }
    int far = (int)~(unsigned)g;
    float4 f = pts[far];
    fx = f.x; fy = f.y; fz = f.z;
  }
  __syncthreads();
  for (int i = t; i < S; i += BLOCK) {
    float4 f = sel[i];
    float* o = out_xyz + ((size_t)b * S + i) * 3;
    o[0] = f.x; o[1] = f.y; o[2] = f.z;
  }
}

// ---------------- kNN k=20: one wave/query, u64-min-key DPP argmin ----------------
// Query/ref coordinate arrays are views into x-level buffers: batch strides
// LDQ/LDR (points). No global stores in the pass loop (register keep).
__global__ __launch_bounds__(64) void knn20_kernel(const float* __restrict__ q,
                                                   const float* __restrict__ ref,
                                                   int S, int M, int* __restrict__ nidx,
                                                   int LDQ, int LDR) {
#pragma clang fp contract(off)
  int bs = blockIdx.x;
  int b = bs / S, s = bs % S;
  int t = threadIdx.x;
  __shared__ float sd[4096];
  const float* qp = q + ((size_t)b * LDQ + s) * 3;
  float qx = qp[0], qy = qp[1], qz = qp[2];
  float qq = qx * qx + qy * qy + qz * qz;
  const float* rp = ref + (size_t)b * LDR * 3;
  for (int i = t; i < M; i += 64) {
    float rx = rp[3 * i], ry = rp[3 * i + 1], rz = rp[3 * i + 2];
    float rr = rx * rx + ry * ry + rz * rz;
    float dot = qx * rx + qy * ry + qz * rz;
    sd[i] = qq - 2.0f * dot + rr;
  }
  __syncthreads();
  unsigned keep = 0;
  for (int k = 0; k < 20; ++k) {
    unsigned long long best = ~0ull;
    for (int i = t; i < M; i += 64) {
      unsigned long long key =
          ((unsigned long long)__float_as_uint(sd[i]) << 32) | (unsigned)i;
      best = (key < best) ? key : best;
    }
    unsigned kh = (unsigned)(best >> 32), kl = (unsigned)best;
    WAVE_RED_MIN(kh, kl);
    unsigned bi = (unsigned)__builtin_amdgcn_readlane((int)kl, 63);
    if (t == k) keep = bi;
    if (t == 0) sd[bi] = FLT_MAX;
    __syncthreads();
  }
  if (t < 20) nidx[(size_t)bs * 20 + t] = (int)keep;
}

// ---------------- GEMM core macro ----------------
// As padded to [16][68]: staging-write bank (4*kk+m)%32 -> 2-way max (free);
// rows are 272 B so float4 reads stay 16B-aligned.
#define GEMM_BODY(AS_EXPR)                                                        \
  __shared__ alignas(16) float As[16][68];                                        \
  __shared__ float Bs[16][64];                                                    \
  int tx = threadIdx.x & 15, ty = threadIdx.x >> 4;                               \
  int rowBase = blockIdx.y * 64;                                                  \
  int colBase = blockIdx.x * 64;                                                  \
  float acc[4][4] = {};                                                           \
  for (int k0 = 0; k0 < K; k0 += 16) {                                            \
    for (int l = threadIdx.x; l < 1024; l += 256) {                               \
      int m = l >> 4, kk = l & 15;                                                \
      int rr = rowBase + m, kq = k0 + kk;                                         \
      float v = 0.0f;                                                             \
      if (rr < Mrows && kq < K) { AS_EXPR }                                       \
      As[kk][m] = v;                                                              \
    }                                                                             \
    for (int l = threadIdx.x; l < 1024; l += 256) {                               \
      int kk = l >> 6, n = l & 63;                                                \
      int kq = k0 + kk, cc = colBase + n;                                         \
      Bs[kk][n] = (kq < K && cc < N) ? Wm[(size_t)kq * N + cc] : 0.0f;            \
    }                                                                             \
    __syncthreads();                                                              \
    _Pragma("unroll")                                                             \
    for (int kk = 0; kk < 16; ++kk) {                                             \
      const float4 av = *reinterpret_cast<const float4*>(&As[kk][ty * 4]);        \
      const float4 bv = *reinterpret_cast<const float4*>(&Bs[kk][tx * 4]);        \
      acc[0][0] += av.x * bv.x; acc[0][1] += av.x * bv.y;                         \
      acc[0][2] += av.x * bv.z; acc[0][3] += av.x * bv.w;                         \
      acc[1][0] += av.y * bv.x; acc[1][1] += av.y * bv.y;                         \
      acc[1][2] += av.y * bv.z; acc[1][3] += av.y * bv.w;                         \
      acc[2][0] += av.z * bv.x; acc[2][1] += av.z * bv.y;                         \
      acc[2][2] += av.z * bv.z; acc[2][3] += av.z * bv.w;                         \
      acc[3][0] += av.w * bv.x; acc[3][1] += av.w * bv.y;                         \
      acc[3][2] += av.w * bv.z; acc[3][3] += av.w * bv.w;                         \
    }                                                                             \
    __syncthreads();                                                              \
  }                                                                               \
  _Pragma("unroll")                                                               \
  for (int i = 0; i < 4; ++i) {                                                   \
    int row = rowBase + ty * 4 + i;                                               \
    if (row >= Mrows) continue;                                                   \
    _Pragma("unroll")                                                             \
    for (int j = 0; j < 4; ++j) {                                                 \
      int col = colBase + tx * 4 + j;                                             \
      if (col >= N) continue;                                                     \
      float v = acc[i][j] + bias[col];                                            \
      if (RELU) v = fmaxf(v, 0.0f);                                               \
      C[(size_t)row * N + col] = v;                                               \
    }                                                                             \
  }

// plain GEMM (seg head)
__global__ __launch_bounds__(256) void gemm_kernel(const float* __restrict__ A,
                                                   const float* __restrict__ Wm,
                                                   const float* __restrict__ bias,
                                                   float* __restrict__ C,
                                                   int Mrows, int N, int K, int RELU) {
  GEMM_BODY( v = A[(size_t)rr * K + kq]; )
}

// SA GEMM with fused grouping gather: row rr -> (b,s,k20) via nidx.
// xyz-ref view stride LDR; query-point view stride LDQ; feats own stride Mref.
__global__ __launch_bounds__(256) void gemm_sa_kernel(
    const float* __restrict__ xyz, const float* __restrict__ feats,
    const float* __restrict__ new_xyz, const int* __restrict__ nidx,
    const float* __restrict__ Wm, const float* __restrict__ bias,
    float* __restrict__ C, int Mref, int LDR, int S, int LDQ, int Cf,
    int Mrows, int N, int K) {
  const int RELU = 1;
  GEMM_BODY(
    int bs = rr / 20;
    int s_ = bs % S;
    int b = bs / S;
    int id = nidx[rr];
    if (kq < 3)
      v = xyz[((size_t)b * LDR + id) * 3 + kq] - new_xyz[((size_t)b * LDQ + s_) * 3 + kq];
    else
      v = feats[((size_t)b * Mref + id) * Cf + (kq - 3)];
  )
}

// FP GEMM with fused 3-NN interp + skip concat: row rr -> bs
__global__ __launch_bounds__(256) void gemm_fp_kernel(
    const float* __restrict__ fr, const int* __restrict__ idx3,
    const float* __restrict__ w3, const float* __restrict__ skip,
    const float* __restrict__ cls, const float* __restrict__ xyzq,
    const float* __restrict__ nrmq,
    const float* __restrict__ Wm, const float* __restrict__ bias,
    float* __restrict__ C, int Sq, int Mr, int Cr, int Cs, int mode,
    int Mrows, int N, int K) {
  const int RELU = 1;
  GEMM_BODY(
    int bs = rr;
    int b = bs / Sq;
    if (kq < Cr) {
      const int* ii = idx3 + (size_t)bs * 3;
      const float* ww = w3 + (size_t)bs * 3;
      const float* fb = fr + (size_t)b * Mr * Cr;
      v = ww[0] * fb[(size_t)ii[0] * Cr + kq];
      v += ww[1] * fb[(size_t)ii[1] * Cr + kq];
      v += ww[2] * fb[(size_t)ii[2] * Cr + kq];
    } else {
      int cc = kq - Cr;
      if (mode == 0) {
        v = skip[(size_t)bs * Cs + cc];
      } else {
        if (cc < 16) v = cls[(size_t)b * 16 + cc];
        else if (cc < 19) v = xyzq[(size_t)bs * 3 + (cc - 16)];
        else v = nrmq[(size_t)bs * 3 + (cc - 19)];
      }
    }
  )
}

// ---------------- maxpool over K=20 neighbors ----------------
__global__ void maxpool_kernel(const float* __restrict__ H, int SB, int C,
                               float* __restrict__ f) {
  int g = blockIdx.x * 256 + threadIdx.x;
  if (g >= SB * C) return;
  int d = g % C;
  int bs = g / C;
  const float* h = H + (size_t)bs * 20 * C + d;
  float m = h[0];
#pragma unroll
  for (int k = 1; k < 20; ++k) m = fmaxf(m, h[(size_t)k * C]);
  f[g] = m;
}

// ---------------- kNN k=3 + inverse-distance weights (one thread per query) ----------------
__global__ void knn3_kernel(const float* __restrict__ q, const float* __restrict__ ref,
                            int Sq, int M, int* __restrict__ idx3, float* __restrict__ w3,
                            int total, int LDQ, int LDR) {
#pragma clang fp contract(off)
  int g = blockIdx.x * 256 + threadIdx.x;
  if (g >= total) return;
  int b = g / Sq, s = g % Sq;
  const float* qp = q + ((size_t)b * LDQ + s) * 3;
  float qx = qp[0], qy = qp[1], qz = qp[2];
  float qq = qx * qx + qy * qy + qz * qz;
  const float* rp = ref + (size_t)b * LDR * 3;
  float v0 = FLT_MAX, v1 = FLT_MAX, v2 = FLT_MAX;
  int i0 = 0, i1 = 0, i2 = 0;
  for (int i = 0; i < M; ++i) {
    float rx = rp[3 * i], ry = rp[3 * i + 1], rz = rp[3 * i + 2];
    float d = qq - 2.0f * (qx * rx + qy * ry + qz * rz) + (rx * rx + ry * ry + rz * rz);
    if (d < v2) {
      if (d < v1) {
        if (d < v0) { v2 = v1; i2 = i1; v1 = v0; i1 = i0; v0 = d; i0 = i; }
        else { v2 = v1; i2 = i1; v1 = d; i1 = i; }
      } else { v2 = d; i2 = i; }
    }
  }
  int ii[3] = {i0, i1, i2};
  float w[3];
  float wsum = 0.0f;
#pragma unroll
  for (int k = 0; k < 3; ++k) {
    const float* r = rp + (size_t)ii[k] * 3;
    float dx = r[0] - qx, dy = r[1] - qy, dz = r[2] - qz;
    float d = dx * dx + dy * dy + dz * dz;
    w[k] = 1.0f / (d + 1e-8f);
    wsum += w[k];
  }
#pragma unroll
  for (int k = 0; k < 3; ++k) {
    idx3[(size_t)g * 3 + k] = ii[k];
    w3[(size_t)g * 3 + k] = w[k] / wsum;
  }
}

// ---------------- transpose g0 [B,N,128] -> out2 [B,128,N] ----------------
__global__ __launch_bounds__(256) void transpose_g0_kernel(const float* __restrict__ g0,
                                                           float* __restrict__ out2) {
  __shared__ float tile[32][33];
  int n0 = blockIdx.x * 32, c0 = blockIdx.y * 32, b = blockIdx.z;
  int tx = threadIdx.x & 31, ty = threadIdx.x >> 5;  // ty 0..7
#pragma unroll
  for (int j = 0; j < 32; j += 8)
    tile[ty + j][tx] = g0[((size_t)b * NPTS + n0 + ty + j) * 128 + c0 + tx];
  __syncthreads();
#pragma unroll
  for (int j = 0; j < 32; j += 8)
    out2[((size_t)b * 128 + c0 + ty + j) * NPTS + n0 + tx] = tile[tx][ty + j];
}

// ---------------- host-side orchestration ----------------
static inline int cdiv(int a, int b) { return (a + b - 1) / b; }

extern "C" void kernel_launch(void* const* d_in, const int* in_sizes, int n_in,
                              void* d_out, int out_size, void* d_ws, size_t ws_size,
                              hipStream_t stream) {
  const float* x    = (const float*)d_in[0];
  const float* cls  = (const float*)d_in[1];
  const float* W0 = (const float*)d_in[2];  const float* b0 = (const float*)d_in[3];
  const float* W1 = (const float*)d_in[4];  const float* b1 = (const float*)d_in[5];
  const float* W2 = (const float*)d_in[6];  const float* b2 = (const float*)d_in[7];
  const float* W3 = (const float*)d_in[8];  const float* b3 = (const float*)d_in[9];
  const float* F3 = (const float*)d_in[10]; const float* fb3 = (const float*)d_in[11];
  const float* F2 = (const float*)d_in[12]; const float* fb2 = (const float*)d_in[13];
  const float* F1 = (const float*)d_in[14]; const float* fb1 = (const float*)d_in[15];
  const float* F0 = (const float*)d_in[16]; const float* fb0 = (const float*)d_in[17];
  const float* Wseg = (const float*)d_in[18]; const float* bseg = (const float*)d_in[19];
  float* out = (float*)d_out;

  float* ws = (float*)d_ws;
  size_t off = 0;
  auto alloc = [&](size_t n) { float* p = ws + off; off += (n + 3) & ~(size_t)3; return p; };
  float* xyz = alloc(8 * 4096 * 3);
  float* nrm = alloc(8 * 4096 * 3);
  float* x1 = alloc(8 * 512 * 3);          // x2/x3/x4 are per-batch PREFIXES of x1
  float* f1 = alloc(8 * 512 * 64);
  float* f2 = alloc(8 * 256 * 128);
  float* f3 = alloc(8 * 128 * 256);
  float* f4 = alloc(8 * 64 * 512);
  float* g3 = alloc(8 * 128 * 512);
  float* g2 = alloc(8 * 256 * 256);
  float* g1 = alloc(8 * 512 * 128);
  float* g0 = alloc(8 * 4096 * 128);
  float* w3buf = alloc(8 * 4096 * 3);
  float* Hbuf = alloc(8 * 512 * 20 * 64);  // SA hidden scratch (5.24M floats max)
  int* nidx = (int*)alloc(8 * 512 * 20);
  int* idx3 = (int*)alloc(8 * 4096 * 3);

  // 0. split/transpose input
  split_xyz_kernel<<<cdiv(8 * 4096, 256), 256, 0, stream>>>(x, xyz, nrm);

  // ---- SA1: 4096 -> 512, C 3 -> 64 (Cin 6) ----
  fps4_kernel<256, 16><<<8, 256, 0, stream>>>(xyz, 4096, 512, x1);
  knn20_kernel<<<8 * 512, 64, 0, stream>>>(x1, xyz, 512, 4096, nidx, 512, 4096);
  {
    dim3 grid(1, cdiv(8 * 512 * 20, 64));
    gemm_sa_kernel<<<grid, 256, 0, stream>>>(xyz, nrm, x1, nidx, W0, b0, Hbuf,
                                             4096, 4096, 512, 512, 3,
                                             8 * 512 * 20, 64, 6);
    maxpool_kernel<<<cdiv(8 * 512 * 64, 256), 256, 0, stream>>>(Hbuf, 8 * 512, 64, f1);
  }

  // ---- SA2: 512 -> 256 (x2 = x1 prefix), C 64 -> 128 (Cin 67) ----
  knn20_kernel<<<8 * 256, 64, 0, stream>>>(x1, x1, 256, 512, nidx, 512, 512);
  {
    dim3 grid(2, cdiv(8 * 256 * 20, 64));
    gemm_sa_kernel<<<grid, 256, 0, stream>>>(x1, f1, x1, nidx, W1, b1, Hbuf,
                                             512, 512, 256, 512, 64,
                                             8 * 256 * 20, 128, 67);
    maxpool_kernel<<<cdiv(8 * 256 * 128, 256), 256, 0, stream>>>(Hbuf, 8 * 256, 128, f2);
  }

  // ---- SA3: 256 -> 128 (x3 = x1 prefix), C 128 -> 256 (Cin 131) ----
  knn20_kernel<<<8 * 128, 64, 0, stream>>>(x1, x1, 128, 256, nidx, 512, 512);
  {
    dim3 grid(4, cdiv(8 * 128 * 20, 64));
    gemm_sa_kernel<<<grid, 256, 0, stream>>>(x1, f2, x1, nidx, W2, b2, Hbuf,
                                             256, 512, 128, 512, 128,
                                             8 * 128 * 20, 256, 131);
    maxpool_kernel<<<cdiv(8 * 128 * 256, 256), 256, 0, stream>>>(Hbuf, 8 * 128, 256, f3);
  }

  // ---- SA4: 128 -> 64 (x4 = x1 prefix), C 256 -> 512 (Cin 259) ----
  knn20_kernel<<<8 * 64, 64, 0, stream>>>(x1, x1, 64, 128, nidx, 512, 512);
  {
    dim3 grid(8, cdiv(8 * 64 * 20, 64));
    gemm_sa_kernel<<<grid, 256, 0, stream>>>(x1, f3, x1, nidx, W3, b3, Hbuf,
                                             128, 512, 64, 512, 256,
                                             8 * 64 * 20, 512, 259);
    maxpool_kernel<<<cdiv(8 * 64 * 512, 256), 256, 0, stream>>>(Hbuf, 8 * 64, 512, f4);
  }

  // ---- FP3: interp f4 (x4->x3) + skip f3 -> g3 [B,128,512] ----
  knn3_kernel<<<cdiv(8 * 128, 256), 256, 0, stream>>>(x1, x1, 128, 64, idx3, w3buf,
                                                      8 * 128, 512, 512);
  {
    dim3 grid(8, cdiv(8 * 128, 64));
    gemm_fp_kernel<<<grid, 256, 0, stream>>>(f4, idx3, w3buf, f3, nullptr, nullptr, nullptr,
                                             F3, fb3, g3, 128, 64, 512, 256, 0,
                                             8 * 128, 512, 768);
  }

  // ---- FP2: interp g3 (x3->x2) + skip f2 -> g2 [B,256,256] ----
  knn3_kernel<<<cdiv(8 * 256, 256), 256, 0, stream>>>(x1, x1, 256, 128, idx3, w3buf,
                                                      8 * 256, 512, 512);
  {
    dim3 grid(4, cdiv(8 * 256, 64));
    gemm_fp_kernel<<<grid, 256, 0, stream>>>(g3, idx3, w3buf, f2, nullptr, nullptr, nullptr,
                                             F2, fb2, g2, 256, 128, 512, 128, 0,
                                             8 * 256, 256, 640);
  }

  // ---- FP1: interp g2 (x2->x1) + skip f1 -> g1 [B,512,128] ----
  knn3_kernel<<<cdiv(8 * 512, 256), 256, 0, stream>>>(x1, x1, 512, 256, idx3, w3buf,
                                                      8 * 512, 512, 512);
  {
    dim3 grid(2, cdiv(8 * 512, 64));
    gemm_fp_kernel<<<grid, 256, 0, stream>>>(g2, idx3, w3buf, f1, nullptr, nullptr, nullptr,
                                             F1, fb1, g1, 512, 256, 256, 64, 0,
                                             8 * 512, 128, 320);
  }

  // ---- FP0: interp g1 (x1->xyz) + skip [cls,xyz,nrm] -> g0 [B,4096,128] ----
  knn3_kernel<<<cdiv(8 * 4096, 256), 256, 0, stream>>>(xyz, x1, 4096, 512, idx3, w3buf,
                                                       8 * 4096, 4096, 512);
  {
    dim3 grid(2, cdiv(8 * 4096, 64));
    gemm_fp_kernel<<<grid, 256, 0, stream>>>(g1, idx3, w3buf, nullptr, cls, xyz, nrm,
                                             F0, fb0, g0, 4096, 512, 128, 22, 1,
                                             8 * 4096, 128, 150);
  }

  // ---- seg head: out1 = g0 @ Wseg + bseg (no relu) ----
  {
    dim3 grid(1, cdiv(8 * 4096, 64));
    gemm_kernel<<<grid, 256, 0, stream>>>(g0, Wseg, bseg, out, 8 * 4096, 50, 128, 0);
  }
  // ---- out2 = transpose(g0) ----
  transpose_g0_kernel<<<dim3(128, 4, 8), 256, 0, stream>>>(g0, out + (size_t)8 * 4096 * 50);
}